// Round 8
// baseline (216.577 us; speedup 1.0000x reference)
//
#include <hip/hip_runtime.h>

// ---------------------------------------------------------------------------
// RelationNetwork: B=32, C=256, N=64 (8x8), D_G_IN=514, HG=HF=512, D_OUT=256
//
//   h0[b,p,q,h] = relu( U'[b,q,h] + V'[b,p,h] )      (layer0 linear in concat)
//   Block = (b, p-pair): two 64x512 h0 tiles through GEMM1/GEMM2, colsums ->
//   atomicAdd emb; f-MLP as two GEMV kernels.
//   r8: WAVE-STAGGERED K-loops. Each wave starts at ks0 = wave*4 (sum order
//   is free), so the 8 waves occupy 8 different pipeline phases: LDS reads of
//   some waves overlap MFMA bursts of others, breaking the barrier-lockstep
//   [all-read -> all-MFMA] serialization that pinned MfmaUtil at ~45% across
//   r2-r7 (invariant to ILP depth r4-r6 and wave count r7).
//   Also: uv+wswz merged into one launch.
// ---------------------------------------------------------------------------

typedef short short8 __attribute__((ext_vector_type(8)));
typedef float f32x16 __attribute__((ext_vector_type(16)));

__device__ __forceinline__ unsigned short f2bf(float f) {
    unsigned u = __builtin_bit_cast(unsigned, f);
    u = (u + 0x7FFFu + ((u >> 16) & 1u)) >> 16;   // RNE
    return (unsigned short)u;
}

__device__ __forceinline__ unsigned cvt_pk(float a, float b) {
    unsigned r;
    asm("v_cvt_pk_bf16_f32 %0, %1, %2" : "=v"(r) : "v"(a), "v"(b));
    return r;
}

// ---------------------------------------------------------------------------
// Kernel 1 (merged): blocks 0-255: per-object linear terms U', V'.
//                    blocks 256-383: W1,W2 -> bf16 fragment order + zero emb.
// ---------------------------------------------------------------------------
__global__ __launch_bounds__(512) void pre_kernel(
    const float* __restrict__ x, const float* __restrict__ W0,
    const float* __restrict__ b0,
    const float* __restrict__ W1, const float* __restrict__ W2,
    float* __restrict__ Up, float* __restrict__ Vp,
    unsigned short* __restrict__ W1s, unsigned short* __restrict__ W2s,
    float* __restrict__ emb)
{
    __shared__ float xs[256 * 8];
    const int tid = threadIdx.x;

    if (blockIdx.x >= 256) {
        // ---- weight-swizzle part ----
        int gid = (blockIdx.x - 256) * 512 + tid;      // 0..65535
        if (gid < 16384) emb[gid] = 0.f;
        int m = gid >> 15;
        int idx = gid & 32767;            // kg*512 + col
        int col = idx & 511;
        int kg = idx >> 9;                // 0..63
        const float* W = m ? W2 : W1;
        unsigned short* O = m ? W2s : W1s;
        short8 v;
#pragma unroll
        for (int j = 0; j < 8; ++j)
            v[j] = (short)f2bf(W[(size_t)(kg * 8 + j) * 512 + col]);
        *(short8*)(O + (size_t)idx * 8) = v;
        return;
    }

    // ---- U'/V' part ----
    const int blk = blockIdx.x;
    const int b = blk >> 3, n0 = (blk & 7) * 8;

    for (int i = tid; i < 2048; i += 512) {
        int c = i >> 3, r = i & 7;
        xs[i] = x[((size_t)b * 256 + c) * 64 + n0 + r];
    }
    __syncthreads();

    const int h = tid;
    float ua[8], va[8];
#pragma unroll
    for (int r = 0; r < 8; ++r) { ua[r] = 0.f; va[r] = 0.f; }

#pragma unroll 4
    for (int c = 0; c < 256; ++c) {
        float wa = W0[(size_t)c * 512 + h];
        float wb = W0[(size_t)(256 + c) * 512 + h];
#pragma unroll
        for (int r = 0; r < 8; ++r) {
            float xv = xs[c * 8 + r];
            ua[r] += xv * wa;
            va[r] += xv * wb;
        }
    }
    const float w2a = W0[(size_t)512 * 512 + h];
    const float w2b = W0[(size_t)513 * 512 + h];
    const float bb = b0[h];
#pragma unroll
    for (int r = 0; r < 8; ++r) {
        int n = n0 + r;
        float fh = (float)(n >> 3), fw = (float)(n & 7);
        Up[((size_t)b * 64 + n) * 512 + h] = ua[r] - fh * w2a - fw * w2b;
        Vp[((size_t)b * 64 + n) * 512 + h] = va[r] + fh * w2a + fw * w2b + bb;
    }
}

// ---------------------------------------------------------------------------
// Kernel 2: fused main kernel, TWO p-tiles per block, 512 thr = 8 waves.
// Wave w owns h-cols [w*64, w*64+64) for BOTH tiles; K-loop start staggered
// per wave (ks0 = w*4) in both GEMMs. 1024 blocks = (b, pp), chunked XCD
// swizzle. LDS 128KB (2 x 64KB tile, h0 then h1 in place).
// Swizzle byte ^= (q&15)<<4.
// ---------------------------------------------------------------------------
__global__ __launch_bounds__(512, 2) void main_kernel(
    const float* __restrict__ Up, const float* __restrict__ Vp,
    const unsigned short* __restrict__ W1s, const unsigned short* __restrict__ W2s,
    const float* __restrict__ b1, const float* __restrict__ b2,
    float* __restrict__ emb)
{
    extern __shared__ __align__(16) unsigned char lds[];
    unsigned char* T0 = lds;
    unsigned char* T1 = lds + 65536;

    // chunked bijective XCD swizzle: 1024 wgs, 128 per XCD
    const int wg = ((blockIdx.x & 7) << 7) | (blockIdx.x >> 3);
    const int b = wg >> 5, pp = wg & 31;
    const int p0 = pp * 2, p1 = p0 + 1;

    const int tid = threadIdx.x;
    const int lane = tid & 63, wave = tid >> 6;
    const int l31 = lane & 31, lg = lane >> 5;
    const int swz = (l31 & 15) << 4;
    const int wcol = wave * 64;
    const int ks0 = (wave & 7) << 2;          // per-wave K-phase stagger

    // ---- build h0 tiles: issue ALL global loads first, then compute ----
    {
        const int cc = tid & 63;            // col-chunk of 8 (== lane)
        const int r0 = tid >> 6;            // == wave
        float4 u0[8], u1[8];
#pragma unroll
        for (int it = 0; it < 8; ++it) {
            const float* ub = Up + ((size_t)(b * 64 + r0 + it * 8)) * 512 + cc * 8;
            u0[it] = *(const float4*)(ub);
            u1[it] = *(const float4*)(ub + 4);
        }
        const float* vA = Vp + ((size_t)(b * 64 + p0)) * 512 + cc * 8;
        const float* vB = Vp + ((size_t)(b * 64 + p1)) * 512 + cc * 8;
        float4 vA0 = *(const float4*)(vA), vA1 = *(const float4*)(vA + 4);
        float4 vB0 = *(const float4*)(vB), vB1 = *(const float4*)(vB + 4);
#pragma unroll
        for (int it = 0; it < 8; ++it) {
            int row = r0 + it * 8;          // q
            int off = row * 1024 + ((cc * 16) ^ ((row & 15) << 4));
            uint4 w;
            w.x = cvt_pk(fmaxf(u0[it].x + vA0.x, 0.f), fmaxf(u0[it].y + vA0.y, 0.f));
            w.y = cvt_pk(fmaxf(u0[it].z + vA0.z, 0.f), fmaxf(u0[it].w + vA0.w, 0.f));
            w.z = cvt_pk(fmaxf(u1[it].x + vA1.x, 0.f), fmaxf(u1[it].y + vA1.y, 0.f));
            w.w = cvt_pk(fmaxf(u1[it].z + vA1.z, 0.f), fmaxf(u1[it].w + vA1.w, 0.f));
            *(uint4*)(&T0[off]) = w;
            w.x = cvt_pk(fmaxf(u0[it].x + vB0.x, 0.f), fmaxf(u0[it].y + vB0.y, 0.f));
            w.y = cvt_pk(fmaxf(u0[it].z + vB0.z, 0.f), fmaxf(u0[it].w + vB0.w, 0.f));
            w.z = cvt_pk(fmaxf(u1[it].x + vB1.x, 0.f), fmaxf(u1[it].y + vB1.y, 0.f));
            w.w = cvt_pk(fmaxf(u1[it].z + vB1.z, 0.f), fmaxf(u1[it].w + vB1.w, 0.f));
            *(uint4*)(&T1[off]) = w;
        }
    }
    __syncthreads();

    const int arow0 = l31 * 1024;
    const int arow1 = (l31 + 32) * 1024;

    // ---- GEMM1 (swapped): acc[t][hf][qf] = D1[h, q]; staggered K order ----
    f32x16 acc[2][2][2];
#pragma unroll
    for (int t = 0; t < 2; ++t)
#pragma unroll
        for (int i = 0; i < 2; ++i)
#pragma unroll
            for (int j = 0; j < 2; ++j) acc[t][i][j] = (f32x16)0.f;

    {
        const unsigned short* wb = W1s + ((size_t)(lg * 512 + wcol + l31)) * 8;
        int ksp = ks0;
        short8 wn0 = *(const short8*)(wb + (size_t)ksp * 8192);
        short8 wn1 = *(const short8*)(wb + (size_t)ksp * 8192 + 256);
        __builtin_amdgcn_s_setprio(1);
#pragma unroll
        for (int ks = 0; ks < 32; ++ks) {
            short8 cw0 = wn0, cw1 = wn1;
            const int ksn = (ksp + 1) & 31;
            if (ks < 31) {
                wn0 = *(const short8*)(wb + (size_t)ksn * 8192);
                wn1 = *(const short8*)(wb + (size_t)ksn * 8192 + 256);
            }
            int achunk = (ksp * 32 + lg * 16) ^ swz;
            short8 a00 = *(const short8*)(&T0[arow0 + achunk]);
            short8 a01 = *(const short8*)(&T0[arow1 + achunk]);
            short8 a10 = *(const short8*)(&T1[arow0 + achunk]);
            short8 a11 = *(const short8*)(&T1[arow1 + achunk]);
            acc[0][0][0] = __builtin_amdgcn_mfma_f32_32x32x16_bf16(cw0, a00, acc[0][0][0], 0, 0, 0);
            acc[0][1][0] = __builtin_amdgcn_mfma_f32_32x32x16_bf16(cw1, a00, acc[0][1][0], 0, 0, 0);
            acc[0][0][1] = __builtin_amdgcn_mfma_f32_32x32x16_bf16(cw0, a01, acc[0][0][1], 0, 0, 0);
            acc[0][1][1] = __builtin_amdgcn_mfma_f32_32x32x16_bf16(cw1, a01, acc[0][1][1], 0, 0, 0);
            acc[1][0][0] = __builtin_amdgcn_mfma_f32_32x32x16_bf16(cw0, a10, acc[1][0][0], 0, 0, 0);
            acc[1][1][0] = __builtin_amdgcn_mfma_f32_32x32x16_bf16(cw1, a10, acc[1][1][0], 0, 0, 0);
            acc[1][0][1] = __builtin_amdgcn_mfma_f32_32x32x16_bf16(cw0, a11, acc[1][0][1], 0, 0, 0);
            acc[1][1][1] = __builtin_amdgcn_mfma_f32_32x32x16_bf16(cw1, a11, acc[1][1][1], 0, 0, 0);
            ksp = ksn;
        }
        __builtin_amdgcn_s_setprio(0);
    }
    __syncthreads();   // all waves done READING h0

    // ---- h1 = relu(acc + b1) -> bf16 back into T0/T1 ----
    // acc[t][hf][qf] reg r: h = wcol + hf*32 + (r&3) + 8*(r>>2) + 4*lg, q = qf*32 + l31
    {
#pragma unroll
        for (int hf = 0; hf < 2; ++hf) {
#pragma unroll
            for (int g = 0; g < 4; ++g) {
                int h = wcol + hf * 32 + g * 8 + 4 * lg;
                float4 bb = *(const float4*)(b1 + h);
#pragma unroll
                for (int t = 0; t < 2; ++t) {
#pragma unroll
                    for (int qf = 0; qf < 2; ++qf) {
                        int q = qf * 32 + l31;
                        float a0 = fmaxf(acc[t][hf][qf][g * 4 + 0] + bb.x, 0.f);
                        float a1 = fmaxf(acc[t][hf][qf][g * 4 + 1] + bb.y, 0.f);
                        float a2 = fmaxf(acc[t][hf][qf][g * 4 + 2] + bb.z, 0.f);
                        float a3 = fmaxf(acc[t][hf][qf][g * 4 + 3] + bb.w, 0.f);
                        uint2 pk;
                        pk.x = cvt_pk(a0, a1);
                        pk.y = cvt_pk(a2, a3);
                        int off = q * 1024 + ((h * 2) ^ ((q & 15) << 4));
                        unsigned char* Tt = t ? T1 : T0;
                        *(uint2*)(&Tt[off]) = pk;
                    }
                }
            }
        }
    }
    __syncthreads();   // h1 complete

    // ---- GEMM2 (normal): acc2[t][rf][cf] = D2[q, h2]; staggered K order ----
    f32x16 acc2[2][2][2];
#pragma unroll
    for (int t = 0; t < 2; ++t)
#pragma unroll
        for (int i = 0; i < 2; ++i)
#pragma unroll
            for (int j = 0; j < 2; ++j) acc2[t][i][j] = (f32x16)0.f;

    {
        const unsigned short* wb = W2s + ((size_t)(lg * 512 + wcol + l31)) * 8;
        int ksp = ks0;
        short8 wn0 = *(const short8*)(wb + (size_t)ksp * 8192);
        short8 wn1 = *(const short8*)(wb + (size_t)ksp * 8192 + 256);
        __builtin_amdgcn_s_setprio(1);
#pragma unroll
        for (int ks = 0; ks < 32; ++ks) {
            short8 cw0 = wn0, cw1 = wn1;
            const int ksn = (ksp + 1) & 31;
            if (ks < 31) {
                wn0 = *(const short8*)(wb + (size_t)ksn * 8192);
                wn1 = *(const short8*)(wb + (size_t)ksn * 8192 + 256);
            }
            int achunk = (ksp * 32 + lg * 16) ^ swz;
            short8 a00 = *(const short8*)(&T0[arow0 + achunk]);
            short8 a01 = *(const short8*)(&T0[arow1 + achunk]);
            short8 a10 = *(const short8*)(&T1[arow0 + achunk]);
            short8 a11 = *(const short8*)(&T1[arow1 + achunk]);
            acc2[0][0][0] = __builtin_amdgcn_mfma_f32_32x32x16_bf16(a00, cw0, acc2[0][0][0], 0, 0, 0);
            acc2[0][1][0] = __builtin_amdgcn_mfma_f32_32x32x16_bf16(a01, cw0, acc2[0][1][0], 0, 0, 0);
            acc2[0][0][1] = __builtin_amdgcn_mfma_f32_32x32x16_bf16(a00, cw1, acc2[0][0][1], 0, 0, 0);
            acc2[0][1][1] = __builtin_amdgcn_mfma_f32_32x32x16_bf16(a01, cw1, acc2[0][1][1], 0, 0, 0);
            acc2[1][0][0] = __builtin_amdgcn_mfma_f32_32x32x16_bf16(a10, cw0, acc2[1][0][0], 0, 0, 0);
            acc2[1][1][0] = __builtin_amdgcn_mfma_f32_32x32x16_bf16(a11, cw0, acc2[1][1][0], 0, 0, 0);
            acc2[1][0][1] = __builtin_amdgcn_mfma_f32_32x32x16_bf16(a10, cw1, acc2[1][0][1], 0, 0, 0);
            acc2[1][1][1] = __builtin_amdgcn_mfma_f32_32x32x16_bf16(a11, cw1, acc2[1][1][1], 0, 0, 0);
            ksp = ksn;
        }
        __builtin_amdgcn_s_setprio(0);
    }

    // ---- relations = relu(acc2 + b2); column-sum over 128 pair-rows ----
    {
        float s[2];
#pragma unroll
        for (int cf = 0; cf < 2; ++cf) {
            int col = wcol + cf * 32 + l31;
            float bias = b2[col];
            float tt = 0.f;
#pragma unroll
            for (int t = 0; t < 2; ++t)
#pragma unroll
                for (int rf = 0; rf < 2; ++rf)
#pragma unroll
                    for (int reg = 0; reg < 16; ++reg)
                        tt += fmaxf(acc2[t][rf][cf][reg] + bias, 0.f);
            tt += __shfl_xor(tt, 32);
            s[cf] = tt;
        }
        if (lane < 32) {
            unsafeAtomicAdd(&emb[b * 512 + wcol + lane], s[0]);
            unsafeAtomicAdd(&emb[b * 512 + wcol + 32 + lane], s[1]);
        }
    }
}

// ---------------------------------------------------------------------------
// Kernel 3: hs = relu(emb @ fW0 + fb0). 256 blocks = (b, 8 slices of 64 cols).
// ---------------------------------------------------------------------------
__global__ __launch_bounds__(256) void f0_kernel(
    const float* __restrict__ emb, const float* __restrict__ fW0,
    const float* __restrict__ fb0, float* __restrict__ hs)
{
    __shared__ float es[512];
    __shared__ float red[256];
    const int b = blockIdx.x >> 3, s = blockIdx.x & 7;
    const int t = threadIdx.x;
    const int colL = t & 63, cg = t >> 6;
    es[t] = emb[b * 512 + t];
    es[t + 256] = emb[b * 512 + 256 + t];
    __syncthreads();
    const int col = s * 64 + colL;
    float a = 0.f;
    const int c0 = cg * 128;
#pragma unroll 4
    for (int c = c0; c < c0 + 128; ++c)
        a += es[c] * fW0[(size_t)c * 512 + col];
    red[t] = a;
    __syncthreads();
    if (t < 64) {
        float r = red[t] + red[t + 64] + red[t + 128] + red[t + 192] + fb0[col];
        hs[b * 512 + col] = fmaxf(r, 0.f);
    }
}

// ---------------------------------------------------------------------------
// Kernel 4: out = hs @ fW1 + fb1. 128 blocks = (b, 4 slices of 64 cols).
// ---------------------------------------------------------------------------
__global__ __launch_bounds__(256) void f1_kernel(
    const float* __restrict__ hs, const float* __restrict__ fW1,
    const float* __restrict__ fb1, float* __restrict__ out)
{
    __shared__ float es[512];
    __shared__ float red[256];
    const int b = blockIdx.x >> 2, s = blockIdx.x & 3;
    const int t = threadIdx.x;
    const int colL = t & 63, cg = t >> 6;
    es[t] = hs[b * 512 + t];
    es[t + 256] = hs[b * 512 + 256 + t];
    __syncthreads();
    const int col = s * 64 + colL;
    float a = 0.f;
    const int c0 = cg * 128;
#pragma unroll 4
    for (int c = c0; c < c0 + 128; ++c)
        a += es[c] * fW1[(size_t)c * 256 + col];
    red[t] = a;
    __syncthreads();
    if (t < 64) {
        out[b * 256 + col] = red[t] + red[t + 64] + red[t + 128] + red[t + 192] + fb1[col];
    }
}

// ---------------------------------------------------------------------------
extern "C" void kernel_launch(void* const* d_in, const int* in_sizes, int n_in,
                              void* d_out, int out_size, void* d_ws, size_t ws_size,
                              hipStream_t stream)
{
    const float* x   = (const float*)d_in[0];
    const float* gW0 = (const float*)d_in[1];
    const float* gb0 = (const float*)d_in[2];
    const float* gW1 = (const float*)d_in[3];
    const float* gb1 = (const float*)d_in[4];
    const float* gW2 = (const float*)d_in[5];
    const float* gb2 = (const float*)d_in[6];
    const float* fW0 = (const float*)d_in[7];
    const float* fb0 = (const float*)d_in[8];
    const float* fW1 = (const float*)d_in[9];
    const float* fb1 = (const float*)d_in[10];
    float* out = (float*)d_out;

    char* ws = (char*)d_ws;
    float* Up           = (float*)(ws);                                   // 4 MB
    float* Vp           = (float*)(ws + (4 << 20));                       // 4 MB
    unsigned short* W1s = (unsigned short*)(ws + (8 << 20));              // 512 KB
    unsigned short* W2s = (unsigned short*)(ws + (8 << 20) + (512 << 10));// 512 KB
    float* emb          = (float*)(ws + (9 << 20));                       // 64 KB
    float* hs           = (float*)(ws + (9 << 20) + (64 << 10));          // 64 KB

    pre_kernel<<<384, 512, 0, stream>>>(x, gW0, gb0, gW1, gW2, Up, Vp, W1s, W2s, emb);
    main_kernel<<<1024, 512, 131072, stream>>>(Up, Vp, W1s, W2s, gb1, gb2, emb);
    f0_kernel<<<256, 256, 0, stream>>>(emb, fW0, fb0, hs);
    f1_kernel<<<128, 256, 0, stream>>>(hs, fW1, fb1, out);
}

// Round 9
// 190.388 us; speedup vs baseline: 1.1376x; 1.1376x over previous
//
#include <hip/hip_runtime.h>

// ---------------------------------------------------------------------------
// RelationNetwork: B=32, C=256, N=64 (8x8), D_G_IN=514, HG=HF=512, D_OUT=256
//
//   h0[b,p,q,h] = relu( U'[b,q,h] + V'[b,p,h] )      (layer0 linear in concat)
//   Block = (b, p-pair): two 64x512 h0 tiles; GEMM1/GEMM2 via 32x32x16 MFMA;
//   colsums -> atomicAdd emb; f-MLP as two GEMV kernels.
//   r9: LDS-path fix (the invariant ~48% MfmaUtil was LDS-bound, and the
//   conflict counter has been CLIPPED at 2^20 since r2):
//     (a) 8B-granular XOR swizzle (row&15)<<3 -> 16 bank positions, 2-way max
//         (free), replacing 16B swizzle whose 8 positions gave 4-way conflicts
//         on every A-frag read. Reads = 2x ds_read_b64, writes = uint2.
//     (b) wave owns ONE tile x 128 h-cols (acc[4][2]): 2 LDS reads feed
//         8 MFMAs per ks (was 4 reads / 8 MFMAs across 2 tiles) -> LDS
//         traffic per GEMM halves to 512KB/CU, balancing LDS ~= MFMA time.
// ---------------------------------------------------------------------------

typedef short short8 __attribute__((ext_vector_type(8)));
typedef float f32x16 __attribute__((ext_vector_type(16)));

__device__ __forceinline__ unsigned short f2bf(float f) {
    unsigned u = __builtin_bit_cast(unsigned, f);
    u = (u + 0x7FFFu + ((u >> 16) & 1u)) >> 16;   // RNE
    return (unsigned short)u;
}

__device__ __forceinline__ unsigned cvt_pk(float a, float b) {
    unsigned r;
    asm("v_cvt_pk_bf16_f32 %0, %1, %2" : "=v"(r) : "v"(a), "v"(b));
    return r;
}

// read a 16B bf16 fragment from swizzled LDS (two 8B halves)
__device__ __forceinline__ short8 lds_frag(const unsigned char* T, int row, int chunk) {
    const int base = row * 1024;
    const int s = (row & 15) << 3;
    uint2 lo = *(const uint2*)(T + base + (chunk ^ s));
    uint2 hi = *(const uint2*)(T + base + ((chunk + 8) ^ s));
    uint4 u; u.x = lo.x; u.y = lo.y; u.z = hi.x; u.w = hi.y;
    return __builtin_bit_cast(short8, u);
}

// ---------------------------------------------------------------------------
// Kernel 1 (merged): blocks 0-255: per-object linear terms U', V'.
//                    blocks 256-383: W1,W2 -> bf16 fragment order + zero emb.
// ---------------------------------------------------------------------------
__global__ __launch_bounds__(512) void pre_kernel(
    const float* __restrict__ x, const float* __restrict__ W0,
    const float* __restrict__ b0,
    const float* __restrict__ W1, const float* __restrict__ W2,
    float* __restrict__ Up, float* __restrict__ Vp,
    unsigned short* __restrict__ W1s, unsigned short* __restrict__ W2s,
    float* __restrict__ emb)
{
    __shared__ float xs[256 * 8];
    const int tid = threadIdx.x;

    if (blockIdx.x >= 256) {
        int gid = (blockIdx.x - 256) * 512 + tid;      // 0..65535
        if (gid < 16384) emb[gid] = 0.f;
        int m = gid >> 15;
        int idx = gid & 32767;            // kg*512 + col
        int col = idx & 511;
        int kg = idx >> 9;                // 0..63
        const float* W = m ? W2 : W1;
        unsigned short* O = m ? W2s : W1s;
        short8 v;
#pragma unroll
        for (int j = 0; j < 8; ++j)
            v[j] = (short)f2bf(W[(size_t)(kg * 8 + j) * 512 + col]);
        *(short8*)(O + (size_t)idx * 8) = v;
        return;
    }

    const int blk = blockIdx.x;
    const int b = blk >> 3, n0 = (blk & 7) * 8;

    for (int i = tid; i < 2048; i += 512) {
        int c = i >> 3, r = i & 7;
        xs[i] = x[((size_t)b * 256 + c) * 64 + n0 + r];
    }
    __syncthreads();

    const int h = tid;
    float ua[8], va[8];
#pragma unroll
    for (int r = 0; r < 8; ++r) { ua[r] = 0.f; va[r] = 0.f; }

#pragma unroll 4
    for (int c = 0; c < 256; ++c) {
        float wa = W0[(size_t)c * 512 + h];
        float wb = W0[(size_t)(256 + c) * 512 + h];
#pragma unroll
        for (int r = 0; r < 8; ++r) {
            float xv = xs[c * 8 + r];
            ua[r] += xv * wa;
            va[r] += xv * wb;
        }
    }
    const float w2a = W0[(size_t)512 * 512 + h];
    const float w2b = W0[(size_t)513 * 512 + h];
    const float bb = b0[h];
#pragma unroll
    for (int r = 0; r < 8; ++r) {
        int n = n0 + r;
        float fh = (float)(n >> 3), fw = (float)(n & 7);
        Up[((size_t)b * 64 + n) * 512 + h] = ua[r] - fh * w2a - fw * w2b;
        Vp[((size_t)b * 64 + n) * 512 + h] = va[r] + fh * w2a + fw * w2b + bb;
    }
}

// ---------------------------------------------------------------------------
// Kernel 2: fused main kernel. 1024 blocks = (b, pp) chunked XCD swizzle,
// 512 threads = 8 waves. Wave w: tile t = w&1, h-slice = (w>>1)*128 (4 frags).
// Per ks: 2 LDS A-frag reads + 4 weight frags + 8 MFMAs. LDS 128KB dynamic.
// Swizzle: byte ^= (row&15)<<3 (8B granular).
// ---------------------------------------------------------------------------
__global__ __launch_bounds__(512, 2) void main_kernel(
    const float* __restrict__ Up, const float* __restrict__ Vp,
    const unsigned short* __restrict__ W1s, const unsigned short* __restrict__ W2s,
    const float* __restrict__ b1, const float* __restrict__ b2,
    float* __restrict__ emb)
{
    extern __shared__ __align__(16) unsigned char lds[];
    unsigned char* T0 = lds;
    unsigned char* T1 = lds + 65536;

    // chunked bijective XCD swizzle: 1024 wgs, 128 per XCD
    const int wg = ((blockIdx.x & 7) << 7) | (blockIdx.x >> 3);
    const int b = wg >> 5, pp = wg & 31;
    const int p0 = pp * 2, p1 = p0 + 1;

    const int tid = threadIdx.x;
    const int lane = tid & 63, wave = tid >> 6;
    const int l31 = lane & 31, lg = lane >> 5;
    const int t = wave & 1;                         // this wave's tile
    const int wcol = (wave >> 1) << 7;              // h-slice base: 0,128,256,384
    unsigned char* T = t ? T1 : T0;

    // ---- build h0 tiles (each thread: row r0 of BOTH tiles, shared U reads) ----
    {
        const int cc = tid & 63;            // col-chunk of 8
        const int r0 = tid >> 6;            // 0..7
        float4 u0[8], u1[8];
#pragma unroll
        for (int it = 0; it < 8; ++it) {
            const float* ub = Up + ((size_t)(b * 64 + r0 + it * 8)) * 512 + cc * 8;
            u0[it] = *(const float4*)(ub);
            u1[it] = *(const float4*)(ub + 4);
        }
        const float* vA = Vp + ((size_t)(b * 64 + p0)) * 512 + cc * 8;
        const float* vB = Vp + ((size_t)(b * 64 + p1)) * 512 + cc * 8;
        float4 vA0 = *(const float4*)(vA), vA1 = *(const float4*)(vA + 4);
        float4 vB0 = *(const float4*)(vB), vB1 = *(const float4*)(vB + 4);
#pragma unroll
        for (int it = 0; it < 8; ++it) {
            int row = r0 + it * 8;          // q
            int base = row * 1024;
            int s = (row & 15) << 3;
            int x = cc * 16;
            uint2 wlo, whi;
            wlo.x = cvt_pk(fmaxf(u0[it].x + vA0.x, 0.f), fmaxf(u0[it].y + vA0.y, 0.f));
            wlo.y = cvt_pk(fmaxf(u0[it].z + vA0.z, 0.f), fmaxf(u0[it].w + vA0.w, 0.f));
            whi.x = cvt_pk(fmaxf(u1[it].x + vA1.x, 0.f), fmaxf(u1[it].y + vA1.y, 0.f));
            whi.y = cvt_pk(fmaxf(u1[it].z + vA1.z, 0.f), fmaxf(u1[it].w + vA1.w, 0.f));
            *(uint2*)(&T0[base + (x ^ s)]) = wlo;
            *(uint2*)(&T0[base + ((x + 8) ^ s)]) = whi;
            wlo.x = cvt_pk(fmaxf(u0[it].x + vB0.x, 0.f), fmaxf(u0[it].y + vB0.y, 0.f));
            wlo.y = cvt_pk(fmaxf(u0[it].z + vB0.z, 0.f), fmaxf(u0[it].w + vB0.w, 0.f));
            whi.x = cvt_pk(fmaxf(u1[it].x + vB1.x, 0.f), fmaxf(u1[it].y + vB1.y, 0.f));
            whi.y = cvt_pk(fmaxf(u1[it].z + vB1.z, 0.f), fmaxf(u1[it].w + vB1.w, 0.f));
            *(uint2*)(&T1[base + (x ^ s)]) = wlo;
            *(uint2*)(&T1[base + ((x + 8) ^ s)]) = whi;
        }
    }
    __syncthreads();

    // ---- GEMM1 (swapped): acc[hf][qf] = D1[h, q] for this wave's tile ----
    f32x16 acc[4][2];
#pragma unroll
    for (int i = 0; i < 4; ++i)
#pragma unroll
        for (int j = 0; j < 2; ++j) acc[i][j] = (f32x16)0.f;

    {
        const unsigned short* wb = W1s + ((size_t)(lg * 512 + wcol + l31)) * 8;
        short8 wn0 = *(const short8*)(wb);
        short8 wn1 = *(const short8*)(wb + 256);
        short8 wn2 = *(const short8*)(wb + 512);
        short8 wn3 = *(const short8*)(wb + 768);
        __builtin_amdgcn_s_setprio(1);
#pragma unroll
        for (int ks = 0; ks < 32; ++ks) {
            short8 cw0 = wn0, cw1 = wn1, cw2 = wn2, cw3 = wn3;
            if (ks < 31) {
                const unsigned short* np = wb + (size_t)(ks + 1) * 8192;
                wn0 = *(const short8*)(np);
                wn1 = *(const short8*)(np + 256);
                wn2 = *(const short8*)(np + 512);
                wn3 = *(const short8*)(np + 768);
            }
            int chunk = ks * 32 + lg * 16;
            short8 a0 = lds_frag(T, l31, chunk);        // q = l31
            short8 a1 = lds_frag(T, l31 + 32, chunk);   // q = l31+32
            acc[0][0] = __builtin_amdgcn_mfma_f32_32x32x16_bf16(cw0, a0, acc[0][0], 0, 0, 0);
            acc[1][0] = __builtin_amdgcn_mfma_f32_32x32x16_bf16(cw1, a0, acc[1][0], 0, 0, 0);
            acc[2][0] = __builtin_amdgcn_mfma_f32_32x32x16_bf16(cw2, a0, acc[2][0], 0, 0, 0);
            acc[3][0] = __builtin_amdgcn_mfma_f32_32x32x16_bf16(cw3, a0, acc[3][0], 0, 0, 0);
            acc[0][1] = __builtin_amdgcn_mfma_f32_32x32x16_bf16(cw0, a1, acc[0][1], 0, 0, 0);
            acc[1][1] = __builtin_amdgcn_mfma_f32_32x32x16_bf16(cw1, a1, acc[1][1], 0, 0, 0);
            acc[2][1] = __builtin_amdgcn_mfma_f32_32x32x16_bf16(cw2, a1, acc[2][1], 0, 0, 0);
            acc[3][1] = __builtin_amdgcn_mfma_f32_32x32x16_bf16(cw3, a1, acc[3][1], 0, 0, 0);
        }
        __builtin_amdgcn_s_setprio(0);
    }
    __syncthreads();   // all waves done READING h0

    // ---- h1 = relu(acc + b1) -> bf16 into this wave's tile (in place) ----
    // acc[hf][qf] reg r: h = wcol + hf*32 + (r&3) + 8*(r>>2) + 4*lg, q = qf*32 + l31
    {
#pragma unroll
        for (int hf = 0; hf < 4; ++hf) {
#pragma unroll
            for (int g = 0; g < 4; ++g) {
                int h = wcol + hf * 32 + g * 8 + 4 * lg;
                float4 bb = *(const float4*)(b1 + h);
#pragma unroll
                for (int qf = 0; qf < 2; ++qf) {
                    int q = qf * 32 + l31;
                    float a0 = fmaxf(acc[hf][qf][g * 4 + 0] + bb.x, 0.f);
                    float a1 = fmaxf(acc[hf][qf][g * 4 + 1] + bb.y, 0.f);
                    float a2 = fmaxf(acc[hf][qf][g * 4 + 2] + bb.z, 0.f);
                    float a3 = fmaxf(acc[hf][qf][g * 4 + 3] + bb.w, 0.f);
                    uint2 pk;
                    pk.x = cvt_pk(a0, a1);
                    pk.y = cvt_pk(a2, a3);
                    int off = q * 1024 + ((h * 2) ^ ((q & 15) << 3));
                    *(uint2*)(&T[off]) = pk;
                }
            }
        }
    }
    __syncthreads();   // h1 complete

    // ---- GEMM2 (normal): acc2[qf][cf] = D2[q, h2] for this wave's tile ----
    f32x16 acc2[2][4];
#pragma unroll
    for (int i = 0; i < 2; ++i)
#pragma unroll
        for (int j = 0; j < 4; ++j) acc2[i][j] = (f32x16)0.f;

    {
        const unsigned short* wb = W2s + ((size_t)(lg * 512 + wcol + l31)) * 8;
        short8 wn0 = *(const short8*)(wb);
        short8 wn1 = *(const short8*)(wb + 256);
        short8 wn2 = *(const short8*)(wb + 512);
        short8 wn3 = *(const short8*)(wb + 768);
        __builtin_amdgcn_s_setprio(1);
#pragma unroll
        for (int ks = 0; ks < 32; ++ks) {
            short8 cw0 = wn0, cw1 = wn1, cw2 = wn2, cw3 = wn3;
            if (ks < 31) {
                const unsigned short* np = wb + (size_t)(ks + 1) * 8192;
                wn0 = *(const short8*)(np);
                wn1 = *(const short8*)(np + 256);
                wn2 = *(const short8*)(np + 512);
                wn3 = *(const short8*)(np + 768);
            }
            int chunk = ks * 32 + lg * 16;
            short8 a0 = lds_frag(T, l31, chunk);        // h1[q=l31, k..]
            short8 a1 = lds_frag(T, l31 + 32, chunk);   // h1[q=l31+32, k..]
            acc2[0][0] = __builtin_amdgcn_mfma_f32_32x32x16_bf16(a0, cw0, acc2[0][0], 0, 0, 0);
            acc2[1][0] = __builtin_amdgcn_mfma_f32_32x32x16_bf16(a1, cw0, acc2[1][0], 0, 0, 0);
            acc2[0][1] = __builtin_amdgcn_mfma_f32_32x32x16_bf16(a0, cw1, acc2[0][1], 0, 0, 0);
            acc2[1][1] = __builtin_amdgcn_mfma_f32_32x32x16_bf16(a1, cw1, acc2[1][1], 0, 0, 0);
            acc2[0][2] = __builtin_amdgcn_mfma_f32_32x32x16_bf16(a0, cw2, acc2[0][2], 0, 0, 0);
            acc2[1][2] = __builtin_amdgcn_mfma_f32_32x32x16_bf16(a1, cw2, acc2[1][2], 0, 0, 0);
            acc2[0][3] = __builtin_amdgcn_mfma_f32_32x32x16_bf16(a0, cw3, acc2[0][3], 0, 0, 0);
            acc2[1][3] = __builtin_amdgcn_mfma_f32_32x32x16_bf16(a1, cw3, acc2[1][3], 0, 0, 0);
        }
        __builtin_amdgcn_s_setprio(0);
    }

    // ---- relations = relu(acc2 + b2); column-sum over this tile's 64 rows ----
    {
#pragma unroll
        for (int cf = 0; cf < 4; ++cf) {
            int col = wcol + cf * 32 + l31;
            float bias = b2[col];
            float tt = 0.f;
#pragma unroll
            for (int qf = 0; qf < 2; ++qf)
#pragma unroll
                for (int reg = 0; reg < 16; ++reg)
                    tt += fmaxf(acc2[qf][cf][reg] + bias, 0.f);
            tt += __shfl_xor(tt, 32);
            if (lane < 32)
                unsafeAtomicAdd(&emb[b * 512 + col], tt);
        }
    }
}

// ---------------------------------------------------------------------------
// Kernel 3: hs = relu(emb @ fW0 + fb0). 256 blocks = (b, 8 slices of 64 cols).
// ---------------------------------------------------------------------------
__global__ __launch_bounds__(256) void f0_kernel(
    const float* __restrict__ emb, const float* __restrict__ fW0,
    const float* __restrict__ fb0, float* __restrict__ hs)
{
    __shared__ float es[512];
    __shared__ float red[256];
    const int b = blockIdx.x >> 3, s = blockIdx.x & 7;
    const int t = threadIdx.x;
    const int colL = t & 63, cg = t >> 6;
    es[t] = emb[b * 512 + t];
    es[t + 256] = emb[b * 512 + 256 + t];
    __syncthreads();
    const int col = s * 64 + colL;
    float a = 0.f;
    const int c0 = cg * 128;
#pragma unroll 4
    for (int c = c0; c < c0 + 128; ++c)
        a += es[c] * fW0[(size_t)c * 512 + col];
    red[t] = a;
    __syncthreads();
    if (t < 64) {
        float r = red[t] + red[t + 64] + red[t + 128] + red[t + 192] + fb0[col];
        hs[b * 512 + col] = fmaxf(r, 0.f);
    }
}

// ---------------------------------------------------------------------------
// Kernel 4: out = hs @ fW1 + fb1. 128 blocks = (b, 4 slices of 64 cols).
// ---------------------------------------------------------------------------
__global__ __launch_bounds__(256) void f1_kernel(
    const float* __restrict__ hs, const float* __restrict__ fW1,
    const float* __restrict__ fb1, float* __restrict__ out)
{
    __shared__ float es[512];
    __shared__ float red[256];
    const int b = blockIdx.x >> 2, s = blockIdx.x & 3;
    const int t = threadIdx.x;
    const int colL = t & 63, cg = t >> 6;
    es[t] = hs[b * 512 + t];
    es[t + 256] = hs[b * 512 + 256 + t];
    __syncthreads();
    const int col = s * 64 + colL;
    float a = 0.f;
    const int c0 = cg * 128;
#pragma unroll 4
    for (int c = c0; c < c0 + 128; ++c)
        a += es[c] * fW1[(size_t)c * 256 + col];
    red[t] = a;
    __syncthreads();
    if (t < 64) {
        out[b * 256 + col] = red[t] + red[t + 64] + red[t + 128] + red[t + 192] + fb1[col];
    }
}

// ---------------------------------------------------------------------------
extern "C" void kernel_launch(void* const* d_in, const int* in_sizes, int n_in,
                              void* d_out, int out_size, void* d_ws, size_t ws_size,
                              hipStream_t stream)
{
    const float* x   = (const float*)d_in[0];
    const float* gW0 = (const float*)d_in[1];
    const float* gb0 = (const float*)d_in[2];
    const float* gW1 = (const float*)d_in[3];
    const float* gb1 = (const float*)d_in[4];
    const float* gW2 = (const float*)d_in[5];
    const float* gb2 = (const float*)d_in[6];
    const float* fW0 = (const float*)d_in[7];
    const float* fb0 = (const float*)d_in[8];
    const float* fW1 = (const float*)d_in[9];
    const float* fb1 = (const float*)d_in[10];
    float* out = (float*)d_out;

    char* ws = (char*)d_ws;
    float* Up           = (float*)(ws);                                   // 4 MB
    float* Vp           = (float*)(ws + (4 << 20));                       // 4 MB
    unsigned short* W1s = (unsigned short*)(ws + (8 << 20));              // 512 KB
    unsigned short* W2s = (unsigned short*)(ws + (8 << 20) + (512 << 10));// 512 KB
    float* emb          = (float*)(ws + (9 << 20));                       // 64 KB
    float* hs           = (float*)(ws + (9 << 20) + (64 << 10));          // 64 KB

    pre_kernel<<<384, 512, 0, stream>>>(x, gW0, gb0, gW1, gW2, Up, Vp, W1s, W2s, emb);
    main_kernel<<<1024, 512, 131072, stream>>>(Up, Vp, W1s, W2s, gb1, gb2, emb);
    f0_kernel<<<256, 256, 0, stream>>>(emb, fW0, fb0, hs);
    f1_kernel<<<128, 256, 0, stream>>>(hs, fW1, fb1, out);
}

// Round 10
// 173.567 us; speedup vs baseline: 1.2478x; 1.0969x over previous
//
#include <hip/hip_runtime.h>

// ---------------------------------------------------------------------------
// RelationNetwork: B=32, C=256, N=64 (8x8), D_G_IN=514, HG=HF=512, D_OUT=256
//
//   h0[b,p,q,h] = relu( U'[b,q,h] + V'[b,p,h] )      (layer0 linear in concat)
//   Block = (b, p-pair): two 64x512 h0 tiles; GEMM1 (swapped) / GEMM2 via
//   32x32x16 bf16 MFMA sharing each weight fragment across 8 MFMAs;
//   colsums -> atomicAdd emb; f-MLP as two GEMV kernels.
//   r10: r4 structure (best-known 127.9us) + weight-load latency cleanup:
//     - GEMM1 weight prologue hoisted ABOVE the build phase (L2 latency hides
//       under build compute; values carried across the barrier in VGPRs).
//     - GEMM2 weight prologue issued at epilogue start (hides under epilogue).
//     - depth-3 rolling weight prefetch (ks%3 slots, compile-time indices).
//   16B swizzle kept: re-derivation shows it is bank-UNIFORM for b128 reads
//   (8 positions x 4 banks x depth 4 = optimal); r9's 8B variant regressed.
// ---------------------------------------------------------------------------

typedef short short8 __attribute__((ext_vector_type(8)));
typedef float f32x16 __attribute__((ext_vector_type(16)));

__device__ __forceinline__ unsigned short f2bf(float f) {
    unsigned u = __builtin_bit_cast(unsigned, f);
    u = (u + 0x7FFFu + ((u >> 16) & 1u)) >> 16;   // RNE
    return (unsigned short)u;
}

__device__ __forceinline__ unsigned cvt_pk(float a, float b) {
    unsigned r;
    asm("v_cvt_pk_bf16_f32 %0, %1, %2" : "=v"(r) : "v"(a), "v"(b));
    return r;
}

// ---------------------------------------------------------------------------
// Kernel 1 (merged): blocks 0-255: per-object linear terms U', V'.
//                    blocks 256-383: W1,W2 -> bf16 fragment order + zero emb.
// ---------------------------------------------------------------------------
__global__ __launch_bounds__(512) void pre_kernel(
    const float* __restrict__ x, const float* __restrict__ W0,
    const float* __restrict__ b0,
    const float* __restrict__ W1, const float* __restrict__ W2,
    float* __restrict__ Up, float* __restrict__ Vp,
    unsigned short* __restrict__ W1s, unsigned short* __restrict__ W2s,
    float* __restrict__ emb)
{
    __shared__ float xs[256 * 8];
    const int tid = threadIdx.x;

    if (blockIdx.x >= 256) {
        int gid = (blockIdx.x - 256) * 512 + tid;      // 0..65535
        if (gid < 16384) emb[gid] = 0.f;
        int m = gid >> 15;
        int idx = gid & 32767;            // kg*512 + col
        int col = idx & 511;
        int kg = idx >> 9;                // 0..63
        const float* W = m ? W2 : W1;
        unsigned short* O = m ? W2s : W1s;
        short8 v;
#pragma unroll
        for (int j = 0; j < 8; ++j)
            v[j] = (short)f2bf(W[(size_t)(kg * 8 + j) * 512 + col]);
        *(short8*)(O + (size_t)idx * 8) = v;
        return;
    }

    const int blk = blockIdx.x;
    const int b = blk >> 3, n0 = (blk & 7) * 8;

    for (int i = tid; i < 2048; i += 512) {
        int c = i >> 3, r = i & 7;
        xs[i] = x[((size_t)b * 256 + c) * 64 + n0 + r];
    }
    __syncthreads();

    const int h = tid;
    float ua[8], va[8];
#pragma unroll
    for (int r = 0; r < 8; ++r) { ua[r] = 0.f; va[r] = 0.f; }

#pragma unroll 4
    for (int c = 0; c < 256; ++c) {
        float wa = W0[(size_t)c * 512 + h];
        float wb = W0[(size_t)(256 + c) * 512 + h];
#pragma unroll
        for (int r = 0; r < 8; ++r) {
            float xv = xs[c * 8 + r];
            ua[r] += xv * wa;
            va[r] += xv * wb;
        }
    }
    const float w2a = W0[(size_t)512 * 512 + h];
    const float w2b = W0[(size_t)513 * 512 + h];
    const float bb = b0[h];
#pragma unroll
    for (int r = 0; r < 8; ++r) {
        int n = n0 + r;
        float fh = (float)(n >> 3), fw = (float)(n & 7);
        Up[((size_t)b * 64 + n) * 512 + h] = ua[r] - fh * w2a - fw * w2b;
        Vp[((size_t)b * 64 + n) * 512 + h] = va[r] + fh * w2a + fw * w2b + bb;
    }
}

// ---------------------------------------------------------------------------
// Kernel 2: fused main kernel, TWO p-tiles per block (r4 structure).
// 1024 blocks = (b, pp) via chunked XCD swizzle; 512 threads = 8 waves;
// wave w owns h-cols [w*64, w*64+64) for BOTH tiles.
// Dynamic LDS 128KB; swizzle byte ^= (q&15)<<4 (bank-uniform for b128).
// ---------------------------------------------------------------------------
__global__ __launch_bounds__(512, 2) void main_kernel(
    const float* __restrict__ Up, const float* __restrict__ Vp,
    const unsigned short* __restrict__ W1s, const unsigned short* __restrict__ W2s,
    const float* __restrict__ b1, const float* __restrict__ b2,
    float* __restrict__ emb)
{
    extern __shared__ __align__(16) unsigned char lds[];
    unsigned char* T0 = lds;
    unsigned char* T1 = lds + 65536;

    // chunked bijective XCD swizzle: 1024 wgs, 128 per XCD
    const int wg = ((blockIdx.x & 7) << 7) | (blockIdx.x >> 3);
    const int b = wg >> 5, pp = wg & 31;
    const int p0 = pp * 2, p1 = p0 + 1;

    const int tid = threadIdx.x;
    const int lane = tid & 63, wave = tid >> 6;
    const int l31 = lane & 31, lg = lane >> 5;
    const int swz = (l31 & 15) << 4;
    const int wcol = wave * 64;

    // GEMM1 weight base + depth-3 prologue: issued BEFORE the build phase so
    // the ~300cyc L2 latency hides under build compute. Values persist in
    // VGPRs across the barrier (its vmcnt(0) drain is then already satisfied).
    const unsigned short* wb1 = W1s + ((size_t)(lg * 512 + wcol + l31)) * 8;
    short8 w1c0[3], w1c1[3];
    w1c0[0] = *(const short8*)(wb1);
    w1c1[0] = *(const short8*)(wb1 + 256);
    w1c0[1] = *(const short8*)(wb1 + 8192);
    w1c1[1] = *(const short8*)(wb1 + 8192 + 256);
    w1c0[2] = *(const short8*)(wb1 + 16384);
    w1c1[2] = *(const short8*)(wb1 + 16384 + 256);

    // ---- build h0 tiles: issue ALL global loads first, then compute ----
    {
        const int cc = tid & 63;            // col-chunk of 8 (== lane)
        const int r0 = tid >> 6;            // == wave
        float4 u0[8], u1[8];
#pragma unroll
        for (int it = 0; it < 8; ++it) {
            const float* ub = Up + ((size_t)(b * 64 + r0 + it * 8)) * 512 + cc * 8;
            u0[it] = *(const float4*)(ub);
            u1[it] = *(const float4*)(ub + 4);
        }
        const float* vA = Vp + ((size_t)(b * 64 + p0)) * 512 + cc * 8;
        const float* vB = Vp + ((size_t)(b * 64 + p1)) * 512 + cc * 8;
        float4 vA0 = *(const float4*)(vA), vA1 = *(const float4*)(vA + 4);
        float4 vB0 = *(const float4*)(vB), vB1 = *(const float4*)(vB + 4);
#pragma unroll
        for (int it = 0; it < 8; ++it) {
            int row = r0 + it * 8;          // q
            int off = row * 1024 + ((cc * 16) ^ ((row & 15) << 4));
            uint4 w;
            w.x = cvt_pk(fmaxf(u0[it].x + vA0.x, 0.f), fmaxf(u0[it].y + vA0.y, 0.f));
            w.y = cvt_pk(fmaxf(u0[it].z + vA0.z, 0.f), fmaxf(u0[it].w + vA0.w, 0.f));
            w.z = cvt_pk(fmaxf(u1[it].x + vA1.x, 0.f), fmaxf(u1[it].y + vA1.y, 0.f));
            w.w = cvt_pk(fmaxf(u1[it].z + vA1.z, 0.f), fmaxf(u1[it].w + vA1.w, 0.f));
            *(uint4*)(&T0[off]) = w;
            w.x = cvt_pk(fmaxf(u0[it].x + vB0.x, 0.f), fmaxf(u0[it].y + vB0.y, 0.f));
            w.y = cvt_pk(fmaxf(u0[it].z + vB0.z, 0.f), fmaxf(u0[it].w + vB0.w, 0.f));
            w.z = cvt_pk(fmaxf(u1[it].x + vB1.x, 0.f), fmaxf(u1[it].y + vB1.y, 0.f));
            w.w = cvt_pk(fmaxf(u1[it].z + vB1.z, 0.f), fmaxf(u1[it].w + vB1.w, 0.f));
            *(uint4*)(&T1[off]) = w;
        }
    }
    __syncthreads();

    const int arow0 = l31 * 1024;
    const int arow1 = (l31 + 32) * 1024;

    // ---- GEMM1 (swapped): acc[t][hf][qf] = D1[h, q]; depth-3 W prefetch ----
    f32x16 acc[2][2][2];
#pragma unroll
    for (int t = 0; t < 2; ++t)
#pragma unroll
        for (int i = 0; i < 2; ++i)
#pragma unroll
            for (int j = 0; j < 2; ++j) acc[t][i][j] = (f32x16)0.f;

    {
        __builtin_amdgcn_s_setprio(1);
#pragma unroll
        for (int ks = 0; ks < 32; ++ks) {
            const int par = ks % 3;
            short8 cw0 = w1c0[par], cw1 = w1c1[par];
            if (ks < 29) {
                const unsigned short* np = wb1 + (size_t)(ks + 3) * 8192;
                w1c0[par] = *(const short8*)(np);
                w1c1[par] = *(const short8*)(np + 256);
            }
            int achunk = (ks * 32 + lg * 16) ^ swz;
            short8 a00 = *(const short8*)(&T0[arow0 + achunk]);
            short8 a01 = *(const short8*)(&T0[arow1 + achunk]);
            short8 a10 = *(const short8*)(&T1[arow0 + achunk]);
            short8 a11 = *(const short8*)(&T1[arow1 + achunk]);
            acc[0][0][0] = __builtin_amdgcn_mfma_f32_32x32x16_bf16(cw0, a00, acc[0][0][0], 0, 0, 0);
            acc[0][1][0] = __builtin_amdgcn_mfma_f32_32x32x16_bf16(cw1, a00, acc[0][1][0], 0, 0, 0);
            acc[0][0][1] = __builtin_amdgcn_mfma_f32_32x32x16_bf16(cw0, a01, acc[0][0][1], 0, 0, 0);
            acc[0][1][1] = __builtin_amdgcn_mfma_f32_32x32x16_bf16(cw1, a01, acc[0][1][1], 0, 0, 0);
            acc[1][0][0] = __builtin_amdgcn_mfma_f32_32x32x16_bf16(cw0, a10, acc[1][0][0], 0, 0, 0);
            acc[1][1][0] = __builtin_amdgcn_mfma_f32_32x32x16_bf16(cw1, a10, acc[1][1][0], 0, 0, 0);
            acc[1][0][1] = __builtin_amdgcn_mfma_f32_32x32x16_bf16(cw0, a11, acc[1][0][1], 0, 0, 0);
            acc[1][1][1] = __builtin_amdgcn_mfma_f32_32x32x16_bf16(cw1, a11, acc[1][1][1], 0, 0, 0);
        }
        __builtin_amdgcn_s_setprio(0);
    }
    __syncthreads();   // all waves done READING h0

    // GEMM2 weight depth-3 prologue: issue now so latency hides under the
    // h1 epilogue's VALU work (lands before the h1 barrier).
    const unsigned short* wb2 = W2s + ((size_t)(lg * 512 + wcol + l31)) * 8;
    short8 w2c0[3], w2c1[3];
    w2c0[0] = *(const short8*)(wb2);
    w2c1[0] = *(const short8*)(wb2 + 256);
    w2c0[1] = *(const short8*)(wb2 + 8192);
    w2c1[1] = *(const short8*)(wb2 + 8192 + 256);
    w2c0[2] = *(const short8*)(wb2 + 16384);
    w2c1[2] = *(const short8*)(wb2 + 16384 + 256);

    // ---- h1 = relu(acc + b1) -> bf16 back into T0/T1 ----
    // acc[t][hf][qf] reg r: h = wcol + hf*32 + (r&3) + 8*(r>>2) + 4*lg, q = qf*32 + l31
    {
#pragma unroll
        for (int hf = 0; hf < 2; ++hf) {
#pragma unroll
            for (int g = 0; g < 4; ++g) {
                int h = wcol + hf * 32 + g * 8 + 4 * lg;
                float4 bb = *(const float4*)(b1 + h);
#pragma unroll
                for (int t = 0; t < 2; ++t) {
#pragma unroll
                    for (int qf = 0; qf < 2; ++qf) {
                        int q = qf * 32 + l31;
                        float a0 = fmaxf(acc[t][hf][qf][g * 4 + 0] + bb.x, 0.f);
                        float a1 = fmaxf(acc[t][hf][qf][g * 4 + 1] + bb.y, 0.f);
                        float a2 = fmaxf(acc[t][hf][qf][g * 4 + 2] + bb.z, 0.f);
                        float a3 = fmaxf(acc[t][hf][qf][g * 4 + 3] + bb.w, 0.f);
                        uint2 pk;
                        pk.x = cvt_pk(a0, a1);
                        pk.y = cvt_pk(a2, a3);
                        int off = q * 1024 + ((h * 2) ^ ((q & 15) << 4));
                        unsigned char* Tt = t ? T1 : T0;
                        *(uint2*)(&Tt[off]) = pk;
                    }
                }
            }
        }
    }
    __syncthreads();   // h1 complete

    // ---- GEMM2 (normal): acc2[t][rf][cf] = D2[q, h2]; depth-3 W prefetch ----
    f32x16 acc2[2][2][2];
#pragma unroll
    for (int t = 0; t < 2; ++t)
#pragma unroll
        for (int i = 0; i < 2; ++i)
#pragma unroll
            for (int j = 0; j < 2; ++j) acc2[t][i][j] = (f32x16)0.f;

    {
        __builtin_amdgcn_s_setprio(1);
#pragma unroll
        for (int ks = 0; ks < 32; ++ks) {
            const int par = ks % 3;
            short8 cw0 = w2c0[par], cw1 = w2c1[par];
            if (ks < 29) {
                const unsigned short* np = wb2 + (size_t)(ks + 3) * 8192;
                w2c0[par] = *(const short8*)(np);
                w2c1[par] = *(const short8*)(np + 256);
            }
            int achunk = (ks * 32 + lg * 16) ^ swz;
            short8 a00 = *(const short8*)(&T0[arow0 + achunk]);
            short8 a01 = *(const short8*)(&T0[arow1 + achunk]);
            short8 a10 = *(const short8*)(&T1[arow0 + achunk]);
            short8 a11 = *(const short8*)(&T1[arow1 + achunk]);
            acc2[0][0][0] = __builtin_amdgcn_mfma_f32_32x32x16_bf16(a00, cw0, acc2[0][0][0], 0, 0, 0);
            acc2[0][1][0] = __builtin_amdgcn_mfma_f32_32x32x16_bf16(a01, cw0, acc2[0][1][0], 0, 0, 0);
            acc2[0][0][1] = __builtin_amdgcn_mfma_f32_32x32x16_bf16(a00, cw1, acc2[0][0][1], 0, 0, 0);
            acc2[0][1][1] = __builtin_amdgcn_mfma_f32_32x32x16_bf16(a01, cw1, acc2[0][1][1], 0, 0, 0);
            acc2[1][0][0] = __builtin_amdgcn_mfma_f32_32x32x16_bf16(a10, cw0, acc2[1][0][0], 0, 0, 0);
            acc2[1][1][0] = __builtin_amdgcn_mfma_f32_32x32x16_bf16(a11, cw0, acc2[1][1][0], 0, 0, 0);
            acc2[1][0][1] = __builtin_amdgcn_mfma_f32_32x32x16_bf16(a10, cw1, acc2[1][0][1], 0, 0, 0);
            acc2[1][1][1] = __builtin_amdgcn_mfma_f32_32x32x16_bf16(a11, cw1, acc2[1][1][1], 0, 0, 0);
        }
        __builtin_amdgcn_s_setprio(0);
    }

    // ---- relations = relu(acc2 + b2); column-sum over 128 pair-rows ----
    {
        float s[2];
#pragma unroll
        for (int cf = 0; cf < 2; ++cf) {
            int col = wcol + cf * 32 + l31;
            float bias = b2[col];
            float tt = 0.f;
#pragma unroll
            for (int t = 0; t < 2; ++t)
#pragma unroll
                for (int rf = 0; rf < 2; ++rf)
#pragma unroll
                    for (int reg = 0; reg < 16; ++reg)
                        tt += fmaxf(acc2[t][rf][cf][reg] + bias, 0.f);
            tt += __shfl_xor(tt, 32);
            s[cf] = tt;
        }
        if (lane < 32) {
            unsafeAtomicAdd(&emb[b * 512 + wcol + lane], s[0]);
            unsafeAtomicAdd(&emb[b * 512 + wcol + 32 + lane], s[1]);
        }
    }
}

// ---------------------------------------------------------------------------
// Kernel 3: hs = relu(emb @ fW0 + fb0). 256 blocks = (b, 8 slices of 64 cols).
// ---------------------------------------------------------------------------
__global__ __launch_bounds__(256) void f0_kernel(
    const float* __restrict__ emb, const float* __restrict__ fW0,
    const float* __restrict__ fb0, float* __restrict__ hs)
{
    __shared__ float es[512];
    __shared__ float red[256];
    const int b = blockIdx.x >> 3, s = blockIdx.x & 7;
    const int t = threadIdx.x;
    const int colL = t & 63, cg = t >> 6;
    es[t] = emb[b * 512 + t];
    es[t + 256] = emb[b * 512 + 256 + t];
    __syncthreads();
    const int col = s * 64 + colL;
    float a = 0.f;
    const int c0 = cg * 128;
#pragma unroll 4
    for (int c = c0; c < c0 + 128; ++c)
        a += es[c] * fW0[(size_t)c * 512 + col];
    red[t] = a;
    __syncthreads();
    if (t < 64) {
        float r = red[t] + red[t + 64] + red[t + 128] + red[t + 192] + fb0[col];
        hs[b * 512 + col] = fmaxf(r, 0.f);
    }
}

// ---------------------------------------------------------------------------
// Kernel 4: out = hs @ fW1 + fb1. 128 blocks = (b, 4 slices of 64 cols).
// ---------------------------------------------------------------------------
__global__ __launch_bounds__(256) void f1_kernel(
    const float* __restrict__ hs, const float* __restrict__ fW1,
    const float* __restrict__ fb1, float* __restrict__ out)
{
    __shared__ float es[512];
    __shared__ float red[256];
    const int b = blockIdx.x >> 2, s = blockIdx.x & 3;
    const int t = threadIdx.x;
    const int colL = t & 63, cg = t >> 6;
    es[t] = hs[b * 512 + t];
    es[t + 256] = hs[b * 512 + 256 + t];
    __syncthreads();
    const int col = s * 64 + colL;
    float a = 0.f;
    const int c0 = cg * 128;
#pragma unroll 4
    for (int c = c0; c < c0 + 128; ++c)
        a += es[c] * fW1[(size_t)c * 256 + col];
    red[t] = a;
    __syncthreads();
    if (t < 64) {
        out[b * 256 + col] = red[t] + red[t + 64] + red[t + 128] + red[t + 192] + fb1[col];
    }
}

// ---------------------------------------------------------------------------
extern "C" void kernel_launch(void* const* d_in, const int* in_sizes, int n_in,
                              void* d_out, int out_size, void* d_ws, size_t ws_size,
                              hipStream_t stream)
{
    const float* x   = (const float*)d_in[0];
    const float* gW0 = (const float*)d_in[1];
    const float* gb0 = (const float*)d_in[2];
    const float* gW1 = (const float*)d_in[3];
    const float* gb1 = (const float*)d_in[4];
    const float* gW2 = (const float*)d_in[5];
    const float* gb2 = (const float*)d_in[6];
    const float* fW0 = (const float*)d_in[7];
    const float* fb0 = (const float*)d_in[8];
    const float* fW1 = (const float*)d_in[9];
    const float* fb1 = (const float*)d_in[10];
    float* out = (float*)d_out;

    char* ws = (char*)d_ws;
    float* Up           = (float*)(ws);                                   // 4 MB
    float* Vp           = (float*)(ws + (4 << 20));                       // 4 MB
    unsigned short* W1s = (unsigned short*)(ws + (8 << 20));              // 512 KB
    unsigned short* W2s = (unsigned short*)(ws + (8 << 20) + (512 << 10));// 512 KB
    float* emb          = (float*)(ws + (9 << 20));                       // 64 KB
    float* hs           = (float*)(ws + (9 << 20) + (64 << 10));          // 64 KB

    pre_kernel<<<384, 512, 0, stream>>>(x, gW0, gb0, gW1, gW2, Up, Vp, W1s, W2s, emb);
    main_kernel<<<1024, 512, 131072, stream>>>(Up, Vp, W1s, W2s, gb1, gb2, emb);
    f0_kernel<<<256, 256, 0, stream>>>(emb, fW0, fb0, hs);
    f1_kernel<<<128, 256, 0, stream>>>(hs, fW1, fb1, out);
}

// Round 11
// 172.251 us; speedup vs baseline: 1.2573x; 1.0076x over previous
//
#include <hip/hip_runtime.h>

// ---------------------------------------------------------------------------
// RelationNetwork: B=32, C=256, N=64 (8x8), D_G_IN=514, HG=HF=512, D_OUT=256
//
//   h0[b,p,q,h] = relu( U'[b,q,h] + V'[b,p,h] )      (layer0 linear in concat)
//   Block = (b, p-pair): two 64x512 h0 tiles; GEMM1 (swapped) / GEMM2 via
//   32x32x16 bf16 MFMA sharing each weight fragment across 8 MFMAs;
//   colsums -> atomicAdd emb; f-MLP as two GEMV kernels.
//   r11: ANTI-PHASE the SIMD partner waves. MFMA blocks its wave (no async),
//   so throughput needs wave A computing while wave B reads. Identical code
//   from one barrier = lockstep = serialization (measured ~1050cyc/ks vs
//   512 MFMA + 385 LDS + 150 W if overlapped). Fix: s_sleep(2) for waves
//   4-7 (SIMD partners of 0-3) after each pre-GEMM barrier; the matrix
//   pipe's own serialization then sustains the offset. Plus T5-style per-ks
//   setprio around the MFMA cluster. Weight prefetch back to depth-2 parity
//   (r10's %3 spilled to scratch: WRITE_SIZE 2->20MB).
// ---------------------------------------------------------------------------

typedef short short8 __attribute__((ext_vector_type(8)));
typedef float f32x16 __attribute__((ext_vector_type(16)));

__device__ __forceinline__ unsigned short f2bf(float f) {
    unsigned u = __builtin_bit_cast(unsigned, f);
    u = (u + 0x7FFFu + ((u >> 16) & 1u)) >> 16;   // RNE
    return (unsigned short)u;
}

__device__ __forceinline__ unsigned cvt_pk(float a, float b) {
    unsigned r;
    asm("v_cvt_pk_bf16_f32 %0, %1, %2" : "=v"(r) : "v"(a), "v"(b));
    return r;
}

// ---------------------------------------------------------------------------
// Kernel 1 (merged): blocks 0-255: per-object linear terms U', V'.
//                    blocks 256-383: W1,W2 -> bf16 fragment order + zero emb.
// ---------------------------------------------------------------------------
__global__ __launch_bounds__(512) void pre_kernel(
    const float* __restrict__ x, const float* __restrict__ W0,
    const float* __restrict__ b0,
    const float* __restrict__ W1, const float* __restrict__ W2,
    float* __restrict__ Up, float* __restrict__ Vp,
    unsigned short* __restrict__ W1s, unsigned short* __restrict__ W2s,
    float* __restrict__ emb)
{
    __shared__ float xs[256 * 8];
    const int tid = threadIdx.x;

    if (blockIdx.x >= 256) {
        int gid = (blockIdx.x - 256) * 512 + tid;      // 0..65535
        if (gid < 16384) emb[gid] = 0.f;
        int m = gid >> 15;
        int idx = gid & 32767;            // kg*512 + col
        int col = idx & 511;
        int kg = idx >> 9;                // 0..63
        const float* W = m ? W2 : W1;
        unsigned short* O = m ? W2s : W1s;
        short8 v;
#pragma unroll
        for (int j = 0; j < 8; ++j)
            v[j] = (short)f2bf(W[(size_t)(kg * 8 + j) * 512 + col]);
        *(short8*)(O + (size_t)idx * 8) = v;
        return;
    }

    const int blk = blockIdx.x;
    const int b = blk >> 3, n0 = (blk & 7) * 8;

    for (int i = tid; i < 2048; i += 512) {
        int c = i >> 3, r = i & 7;
        xs[i] = x[((size_t)b * 256 + c) * 64 + n0 + r];
    }
    __syncthreads();

    const int h = tid;
    float ua[8], va[8];
#pragma unroll
    for (int r = 0; r < 8; ++r) { ua[r] = 0.f; va[r] = 0.f; }

#pragma unroll 4
    for (int c = 0; c < 256; ++c) {
        float wa = W0[(size_t)c * 512 + h];
        float wb = W0[(size_t)(256 + c) * 512 + h];
#pragma unroll
        for (int r = 0; r < 8; ++r) {
            float xv = xs[c * 8 + r];
            ua[r] += xv * wa;
            va[r] += xv * wb;
        }
    }
    const float w2a = W0[(size_t)512 * 512 + h];
    const float w2b = W0[(size_t)513 * 512 + h];
    const float bb = b0[h];
#pragma unroll
    for (int r = 0; r < 8; ++r) {
        int n = n0 + r;
        float fh = (float)(n >> 3), fw = (float)(n & 7);
        Up[((size_t)b * 64 + n) * 512 + h] = ua[r] - fh * w2a - fw * w2b;
        Vp[((size_t)b * 64 + n) * 512 + h] = va[r] + fh * w2a + fw * w2b + bb;
    }
}

// ---------------------------------------------------------------------------
// Kernel 2: fused main kernel, TWO p-tiles per block (r4 structure).
// 1024 blocks = (b, pp) via chunked XCD swizzle; 512 threads = 8 waves;
// wave w owns h-cols [w*64, w*64+64) for BOTH tiles.
// Dynamic LDS 128KB; swizzle byte ^= (q&15)<<4.
// ---------------------------------------------------------------------------
__global__ __launch_bounds__(512, 2) void main_kernel(
    const float* __restrict__ Up, const float* __restrict__ Vp,
    const unsigned short* __restrict__ W1s, const unsigned short* __restrict__ W2s,
    const float* __restrict__ b1, const float* __restrict__ b2,
    float* __restrict__ emb)
{
    extern __shared__ __align__(16) unsigned char lds[];
    unsigned char* T0 = lds;
    unsigned char* T1 = lds + 65536;

    // chunked bijective XCD swizzle: 1024 wgs, 128 per XCD
    const int wg = ((blockIdx.x & 7) << 7) | (blockIdx.x >> 3);
    const int b = wg >> 5, pp = wg & 31;
    const int p0 = pp * 2, p1 = p0 + 1;

    const int tid = threadIdx.x;
    const int lane = tid & 63, wave = tid >> 6;
    const int l31 = lane & 31, lg = lane >> 5;
    const int swz = (l31 & 15) << 4;
    const int wcol = wave * 64;
    const bool late = (wave >= 4);     // SIMD partner group (wave i & i+4 share SIMD i)

    // GEMM1 weight base + depth-2 prologue issued BEFORE build (L2 latency
    // hides under build compute; values carried across the barrier in VGPRs).
    const unsigned short* wb1 = W1s + ((size_t)(lg * 512 + wcol + l31)) * 8;
    short8 w1c0[2], w1c1[2];
    w1c0[0] = *(const short8*)(wb1);
    w1c1[0] = *(const short8*)(wb1 + 256);
    w1c0[1] = *(const short8*)(wb1 + 8192);
    w1c1[1] = *(const short8*)(wb1 + 8192 + 256);

    // ---- build h0 tiles: issue ALL global loads first, then compute ----
    {
        const int cc = tid & 63;            // col-chunk of 8 (== lane)
        const int r0 = tid >> 6;            // == wave
        float4 u0[8], u1[8];
#pragma unroll
        for (int it = 0; it < 8; ++it) {
            const float* ub = Up + ((size_t)(b * 64 + r0 + it * 8)) * 512 + cc * 8;
            u0[it] = *(const float4*)(ub);
            u1[it] = *(const float4*)(ub + 4);
        }
        const float* vA = Vp + ((size_t)(b * 64 + p0)) * 512 + cc * 8;
        const float* vB = Vp + ((size_t)(b * 64 + p1)) * 512 + cc * 8;
        float4 vA0 = *(const float4*)(vA), vA1 = *(const float4*)(vA + 4);
        float4 vB0 = *(const float4*)(vB), vB1 = *(const float4*)(vB + 4);
#pragma unroll
        for (int it = 0; it < 8; ++it) {
            int row = r0 + it * 8;          // q
            int off = row * 1024 + ((cc * 16) ^ ((row & 15) << 4));
            uint4 w;
            w.x = cvt_pk(fmaxf(u0[it].x + vA0.x, 0.f), fmaxf(u0[it].y + vA0.y, 0.f));
            w.y = cvt_pk(fmaxf(u0[it].z + vA0.z, 0.f), fmaxf(u0[it].w + vA0.w, 0.f));
            w.z = cvt_pk(fmaxf(u1[it].x + vA1.x, 0.f), fmaxf(u1[it].y + vA1.y, 0.f));
            w.w = cvt_pk(fmaxf(u1[it].z + vA1.z, 0.f), fmaxf(u1[it].w + vA1.w, 0.f));
            *(uint4*)(&T0[off]) = w;
            w.x = cvt_pk(fmaxf(u0[it].x + vB0.x, 0.f), fmaxf(u0[it].y + vB0.y, 0.f));
            w.y = cvt_pk(fmaxf(u0[it].z + vB0.z, 0.f), fmaxf(u0[it].w + vB0.w, 0.f));
            w.z = cvt_pk(fmaxf(u1[it].x + vB1.x, 0.f), fmaxf(u1[it].y + vB1.y, 0.f));
            w.w = cvt_pk(fmaxf(u1[it].z + vB1.z, 0.f), fmaxf(u1[it].w + vB1.w, 0.f));
            *(uint4*)(&T1[off]) = w;
        }
    }
    __syncthreads();

    // de-phase SIMD partners: waves 4-7 start ~128cyc late; the blocking
    // matrix pipe then sustains the anti-phase (B reads under A's MFMA).
    if (late) __builtin_amdgcn_s_sleep(2);

    const int arow0 = l31 * 1024;
    const int arow1 = (l31 + 32) * 1024;

    // ---- GEMM1 (swapped): acc[t][hf][qf] = D1[h, q]; depth-2 W prefetch ----
    f32x16 acc[2][2][2];
#pragma unroll
    for (int t = 0; t < 2; ++t)
#pragma unroll
        for (int i = 0; i < 2; ++i)
#pragma unroll
            for (int j = 0; j < 2; ++j) acc[t][i][j] = (f32x16)0.f;

    {
#pragma unroll
        for (int ks = 0; ks < 32; ++ks) {
            const int par = ks & 1;
            short8 cw0 = w1c0[par], cw1 = w1c1[par];
            if (ks < 30) {
                const unsigned short* np = wb1 + (size_t)(ks + 2) * 8192;
                w1c0[par] = *(const short8*)(np);
                w1c1[par] = *(const short8*)(np + 256);
            }
            int achunk = (ks * 32 + lg * 16) ^ swz;
            short8 a00 = *(const short8*)(&T0[arow0 + achunk]);
            short8 a01 = *(const short8*)(&T0[arow1 + achunk]);
            short8 a10 = *(const short8*)(&T1[arow0 + achunk]);
            short8 a11 = *(const short8*)(&T1[arow1 + achunk]);
            __builtin_amdgcn_s_setprio(1);
            acc[0][0][0] = __builtin_amdgcn_mfma_f32_32x32x16_bf16(cw0, a00, acc[0][0][0], 0, 0, 0);
            acc[0][1][0] = __builtin_amdgcn_mfma_f32_32x32x16_bf16(cw1, a00, acc[0][1][0], 0, 0, 0);
            acc[0][0][1] = __builtin_amdgcn_mfma_f32_32x32x16_bf16(cw0, a01, acc[0][0][1], 0, 0, 0);
            acc[0][1][1] = __builtin_amdgcn_mfma_f32_32x32x16_bf16(cw1, a01, acc[0][1][1], 0, 0, 0);
            acc[1][0][0] = __builtin_amdgcn_mfma_f32_32x32x16_bf16(cw0, a10, acc[1][0][0], 0, 0, 0);
            acc[1][1][0] = __builtin_amdgcn_mfma_f32_32x32x16_bf16(cw1, a10, acc[1][1][0], 0, 0, 0);
            acc[1][0][1] = __builtin_amdgcn_mfma_f32_32x32x16_bf16(cw0, a11, acc[1][0][1], 0, 0, 0);
            acc[1][1][1] = __builtin_amdgcn_mfma_f32_32x32x16_bf16(cw1, a11, acc[1][1][1], 0, 0, 0);
            __builtin_amdgcn_s_setprio(0);
        }
    }
    __syncthreads();   // all waves done READING h0

    // GEMM2 weight depth-2 prologue: latency hides under the h1 epilogue.
    const unsigned short* wb2 = W2s + ((size_t)(lg * 512 + wcol + l31)) * 8;
    short8 w2c0[2], w2c1[2];
    w2c0[0] = *(const short8*)(wb2);
    w2c1[0] = *(const short8*)(wb2 + 256);
    w2c0[1] = *(const short8*)(wb2 + 8192);
    w2c1[1] = *(const short8*)(wb2 + 8192 + 256);

    // ---- h1 = relu(acc + b1) -> bf16 back into T0/T1 ----
    // acc[t][hf][qf] reg r: h = wcol + hf*32 + (r&3) + 8*(r>>2) + 4*lg, q = qf*32 + l31
    {
#pragma unroll
        for (int hf = 0; hf < 2; ++hf) {
#pragma unroll
            for (int g = 0; g < 4; ++g) {
                int h = wcol + hf * 32 + g * 8 + 4 * lg;
                float4 bb = *(const float4*)(b1 + h);
#pragma unroll
                for (int t = 0; t < 2; ++t) {
#pragma unroll
                    for (int qf = 0; qf < 2; ++qf) {
                        int q = qf * 32 + l31;
                        float a0 = fmaxf(acc[t][hf][qf][g * 4 + 0] + bb.x, 0.f);
                        float a1 = fmaxf(acc[t][hf][qf][g * 4 + 1] + bb.y, 0.f);
                        float a2 = fmaxf(acc[t][hf][qf][g * 4 + 2] + bb.z, 0.f);
                        float a3 = fmaxf(acc[t][hf][qf][g * 4 + 3] + bb.w, 0.f);
                        uint2 pk;
                        pk.x = cvt_pk(a0, a1);
                        pk.y = cvt_pk(a2, a3);
                        int off = q * 1024 + ((h * 2) ^ ((q & 15) << 4));
                        unsigned char* Tt = t ? T1 : T0;
                        *(uint2*)(&Tt[off]) = pk;
                    }
                }
            }
        }
    }
    __syncthreads();   // h1 complete

    if (late) __builtin_amdgcn_s_sleep(2);

    // ---- GEMM2 (normal): acc2[t][rf][cf] = D2[q, h2]; depth-2 W prefetch ----
    f32x16 acc2[2][2][2];
#pragma unroll
    for (int t = 0; t < 2; ++t)
#pragma unroll
        for (int i = 0; i < 2; ++i)
#pragma unroll
            for (int j = 0; j < 2; ++j) acc2[t][i][j] = (f32x16)0.f;

    {
#pragma unroll
        for (int ks = 0; ks < 32; ++ks) {
            const int par = ks & 1;
            short8 cw0 = w2c0[par], cw1 = w2c1[par];
            if (ks < 30) {
                const unsigned short* np = wb2 + (size_t)(ks + 2) * 8192;
                w2c0[par] = *(const short8*)(np);
                w2c1[par] = *(const short8*)(np + 256);
            }
            int achunk = (ks * 32 + lg * 16) ^ swz;
            short8 a00 = *(const short8*)(&T0[arow0 + achunk]);
            short8 a01 = *(const short8*)(&T0[arow1 + achunk]);
            short8 a10 = *(const short8*)(&T1[arow0 + achunk]);
            short8 a11 = *(const short8*)(&T1[arow1 + achunk]);
            __builtin_amdgcn_s_setprio(1);
            acc2[0][0][0] = __builtin_amdgcn_mfma_f32_32x32x16_bf16(a00, cw0, acc2[0][0][0], 0, 0, 0);
            acc2[0][1][0] = __builtin_amdgcn_mfma_f32_32x32x16_bf16(a01, cw0, acc2[0][1][0], 0, 0, 0);
            acc2[0][0][1] = __builtin_amdgcn_mfma_f32_32x32x16_bf16(a00, cw1, acc2[0][0][1], 0, 0, 0);
            acc2[0][1][1] = __builtin_amdgcn_mfma_f32_32x32x16_bf16(a01, cw1, acc2[0][1][1], 0, 0, 0);
            acc2[1][0][0] = __builtin_amdgcn_mfma_f32_32x32x16_bf16(a10, cw0, acc2[1][0][0], 0, 0, 0);
            acc2[1][1][0] = __builtin_amdgcn_mfma_f32_32x32x16_bf16(a11, cw0, acc2[1][1][0], 0, 0, 0);
            acc2[1][0][1] = __builtin_amdgcn_mfma_f32_32x32x16_bf16(a10, cw1, acc2[1][0][1], 0, 0, 0);
            acc2[1][1][1] = __builtin_amdgcn_mfma_f32_32x32x16_bf16(a11, cw1, acc2[1][1][1], 0, 0, 0);
            __builtin_amdgcn_s_setprio(0);
        }
    }

    // ---- relations = relu(acc2 + b2); column-sum over 128 pair-rows ----
    {
        float s[2];
#pragma unroll
        for (int cf = 0; cf < 2; ++cf) {
            int col = wcol + cf * 32 + l31;
            float bias = b2[col];
            float tt = 0.f;
#pragma unroll
            for (int t = 0; t < 2; ++t)
#pragma unroll
                for (int rf = 0; rf < 2; ++rf)
#pragma unroll
                    for (int reg = 0; reg < 16; ++reg)
                        tt += fmaxf(acc2[t][rf][cf][reg] + bias, 0.f);
            tt += __shfl_xor(tt, 32);
            s[cf] = tt;
        }
        if (lane < 32) {
            unsafeAtomicAdd(&emb[b * 512 + wcol + lane], s[0]);
            unsafeAtomicAdd(&emb[b * 512 + wcol + 32 + lane], s[1]);
        }
    }
}

// ---------------------------------------------------------------------------
// Kernel 3: hs = relu(emb @ fW0 + fb0). 256 blocks = (b, 8 slices of 64 cols).
// ---------------------------------------------------------------------------
__global__ __launch_bounds__(256) void f0_kernel(
    const float* __restrict__ emb, const float* __restrict__ fW0,
    const float* __restrict__ fb0, float* __restrict__ hs)
{
    __shared__ float es[512];
    __shared__ float red[256];
    const int b = blockIdx.x >> 3, s = blockIdx.x & 7;
    const int t = threadIdx.x;
    const int colL = t & 63, cg = t >> 6;
    es[t] = emb[b * 512 + t];
    es[t + 256] = emb[b * 512 + 256 + t];
    __syncthreads();
    const int col = s * 64 + colL;
    float a = 0.f;
    const int c0 = cg * 128;
#pragma unroll 4
    for (int c = c0; c < c0 + 128; ++c)
        a += es[c] * fW0[(size_t)c * 512 + col];
    red[t] = a;
    __syncthreads();
    if (t < 64) {
        float r = red[t] + red[t + 64] + red[t + 128] + red[t + 192] + fb0[col];
        hs[b * 512 + col] = fmaxf(r, 0.f);
    }
}

// ---------------------------------------------------------------------------
// Kernel 4: out = hs @ fW1 + fb1. 128 blocks = (b, 4 slices of 64 cols).
// ---------------------------------------------------------------------------
__global__ __launch_bounds__(256) void f1_kernel(
    const float* __restrict__ hs, const float* __restrict__ fW1,
    const float* __restrict__ fb1, float* __restrict__ out)
{
    __shared__ float es[512];
    __shared__ float red[256];
    const int b = blockIdx.x >> 2, s = blockIdx.x & 3;
    const int t = threadIdx.x;
    const int colL = t & 63, cg = t >> 6;
    es[t] = hs[b * 512 + t];
    es[t + 256] = hs[b * 512 + 256 + t];
    __syncthreads();
    const int col = s * 64 + colL;
    float a = 0.f;
    const int c0 = cg * 128;
#pragma unroll 4
    for (int c = c0; c < c0 + 128; ++c)
        a += es[c] * fW1[(size_t)c * 256 + col];
    red[t] = a;
    __syncthreads();
    if (t < 64) {
        out[b * 256 + col] = red[t] + red[t + 64] + red[t + 128] + red[t + 192] + fb1[col];
    }
}

// ---------------------------------------------------------------------------
extern "C" void kernel_launch(void* const* d_in, const int* in_sizes, int n_in,
                              void* d_out, int out_size, void* d_ws, size_t ws_size,
                              hipStream_t stream)
{
    const float* x   = (const float*)d_in[0];
    const float* gW0 = (const float*)d_in[1];
    const float* gb0 = (const float*)d_in[2];
    const float* gW1 = (const float*)d_in[3];
    const float* gb1 = (const float*)d_in[4];
    const float* gW2 = (const float*)d_in[5];
    const float* gb2 = (const float*)d_in[6];
    const float* fW0 = (const float*)d_in[7];
    const float* fb0 = (const float*)d_in[8];
    const float* fW1 = (const float*)d_in[9];
    const float* fb1 = (const float*)d_in[10];
    float* out = (float*)d_out;

    char* ws = (char*)d_ws;
    float* Up           = (float*)(ws);                                   // 4 MB
    float* Vp           = (float*)(ws + (4 << 20));                       // 4 MB
    unsigned short* W1s = (unsigned short*)(ws + (8 << 20));              // 512 KB
    unsigned short* W2s = (unsigned short*)(ws + (8 << 20) + (512 << 10));// 512 KB
    float* emb          = (float*)(ws + (9 << 20));                       // 64 KB
    float* hs           = (float*)(ws + (9 << 20) + (64 << 10));          // 64 KB

    pre_kernel<<<384, 512, 0, stream>>>(x, gW0, gb0, gW1, gW2, Up, Vp, W1s, W2s, emb);
    main_kernel<<<1024, 512, 131072, stream>>>(Up, Vp, W1s, W2s, gb1, gb2, emb);
    f0_kernel<<<256, 256, 0, stream>>>(emb, fW0, fb0, hs);
    f1_kernel<<<128, 256, 0, stream>>>(hs, fW1, fb1, out);
}

// Round 12
// 171.504 us; speedup vs baseline: 1.2628x; 1.0044x over previous
//
#include <hip/hip_runtime.h>

// ---------------------------------------------------------------------------
// RelationNetwork: B=32, C=256, N=64 (8x8), D_G_IN=514, HG=HF=512, D_OUT=256
//
//   h0[b,p,q,h] = relu( U'[b,q,h] + V'[b,p,h] )      (layer0 linear in concat)
//   Block = (b, p-pair): two 64x512 h0 tiles; GEMM1 (swapped) / GEMM2 via
//   32x32x16 bf16 MFMA sharing each weight fragment across 8 MFMAs;
//   colsums -> atomicAdd emb; f-MLP as two GEMV kernels.
//   r12: main = r4-EXACT (empirical optimum 127.9us; six scheduling
//   perturbations r5-r11 all NULL or regressed -> declared plateau).
//   pre_kernel UV part restructured: block = (b, 64-h slice) reads only its
//   W0 column slice (128KB) + stages x[b] in LDS -> W0 traffic 263MB -> 33MB.
// ---------------------------------------------------------------------------

typedef short short8 __attribute__((ext_vector_type(8)));
typedef float f32x16 __attribute__((ext_vector_type(16)));

__device__ __forceinline__ unsigned short f2bf(float f) {
    unsigned u = __builtin_bit_cast(unsigned, f);
    u = (u + 0x7FFFu + ((u >> 16) & 1u)) >> 16;   // RNE
    return (unsigned short)u;
}

__device__ __forceinline__ unsigned cvt_pk(float a, float b) {
    unsigned r;
    asm("v_cvt_pk_bf16_f32 %0, %1, %2" : "=v"(r) : "v"(a), "v"(b));
    return r;
}

// ---------------------------------------------------------------------------
// Kernel 1 (merged): blocks 0-255: UV (h-sliced: blk = b*8 + s, s = h-slice).
//                    blocks 256-383: W1,W2 -> bf16 fragment order + zero emb.
// UV: thread tid = g*64 + hL; handles n in [g*8, g*8+8), h = s*64 + hL.
// x[b] staged in LDS (64KB); W0 slice reads coalesced 64-wide.
// ---------------------------------------------------------------------------
__global__ __launch_bounds__(512) void pre_kernel(
    const float* __restrict__ x, const float* __restrict__ W0,
    const float* __restrict__ b0,
    const float* __restrict__ W1, const float* __restrict__ W2,
    float* __restrict__ Up, float* __restrict__ Vp,
    unsigned short* __restrict__ W1s, unsigned short* __restrict__ W2s,
    float* __restrict__ emb)
{
    __shared__ float xs[256 * 64];          // x[b][c][n], 64KB
    const int tid = threadIdx.x;

    if (blockIdx.x >= 256) {
        // ---- weight-swizzle part ----
        int gid = (blockIdx.x - 256) * 512 + tid;      // 0..65535
        if (gid < 16384) emb[gid] = 0.f;
        int m = gid >> 15;
        int idx = gid & 32767;            // kg*512 + col
        int col = idx & 511;
        int kg = idx >> 9;                // 0..63
        const float* W = m ? W2 : W1;
        unsigned short* O = m ? W2s : W1s;
        short8 v;
#pragma unroll
        for (int j = 0; j < 8; ++j)
            v[j] = (short)f2bf(W[(size_t)(kg * 8 + j) * 512 + col]);
        *(short8*)(O + (size_t)idx * 8) = v;
        return;
    }

    // ---- UV part: blk = b*8 + s ----
    const int b = blockIdx.x >> 3, s = blockIdx.x & 7;
    const int g = tid >> 6;              // n-group 0..7
    const int hL = tid & 63;
    const int h = s * 64 + hL;
    const int n0 = g * 8;

    // stage x[b] (flat 16384 floats, coalesced)
    {
        const float* xb = x + (size_t)b * 16384;
        for (int i = tid; i < 16384; i += 512) xs[i] = xb[i];
    }
    __syncthreads();

    float ua[8], va[8];
#pragma unroll
    for (int r = 0; r < 8; ++r) { ua[r] = 0.f; va[r] = 0.f; }

#pragma unroll 4
    for (int c = 0; c < 256; ++c) {
        float wa = W0[(size_t)c * 512 + h];
        float wb = W0[(size_t)(256 + c) * 512 + h];
        const float* xr = &xs[c * 64 + n0];
#pragma unroll
        for (int r = 0; r < 8; ++r) {
            float xv = xr[r];
            ua[r] += xv * wa;
            va[r] += xv * wb;
        }
    }
    const float w2a = W0[(size_t)512 * 512 + h];
    const float w2b = W0[(size_t)513 * 512 + h];
    const float bb = b0[h];
#pragma unroll
    for (int r = 0; r < 8; ++r) {
        int n = n0 + r;
        float fh = (float)(n >> 3), fw = (float)(n & 7);
        Up[((size_t)b * 64 + n) * 512 + h] = ua[r] - fh * w2a - fw * w2b;
        Vp[((size_t)b * 64 + n) * 512 + h] = va[r] + fh * w2a + fw * w2b + bb;
    }
}

// ---------------------------------------------------------------------------
// Kernel 2: fused main kernel, TWO p-tiles per block (r4-EXACT).
// 1024 blocks = (b, pp) via chunked XCD swizzle; 512 threads = 8 waves;
// wave w owns h-cols [w*64, w*64+64) for BOTH tiles.
// Dynamic LDS 128KB; swizzle byte ^= (q&15)<<4.
// ---------------------------------------------------------------------------
__global__ __launch_bounds__(512, 2) void main_kernel(
    const float* __restrict__ Up, const float* __restrict__ Vp,
    const unsigned short* __restrict__ W1s, const unsigned short* __restrict__ W2s,
    const float* __restrict__ b1, const float* __restrict__ b2,
    float* __restrict__ emb)
{
    extern __shared__ __align__(16) unsigned char lds[];
    unsigned char* T0 = lds;
    unsigned char* T1 = lds + 65536;

    // chunked bijective XCD swizzle: 1024 wgs, 128 per XCD
    const int wg = ((blockIdx.x & 7) << 7) | (blockIdx.x >> 3);
    const int b = wg >> 5, pp = wg & 31;
    const int p0 = pp * 2, p1 = p0 + 1;

    const int tid = threadIdx.x;
    const int lane = tid & 63, wave = tid >> 6;
    const int l31 = lane & 31, lg = lane >> 5;
    const int swz = (l31 & 15) << 4;
    const int wcol = wave * 64;

    // ---- build h0 tiles: issue ALL global loads first, then compute ----
    {
        const int cc = tid & 63;            // col-chunk of 8 (== lane)
        const int r0 = tid >> 6;            // == wave
        float4 u0[8], u1[8];
#pragma unroll
        for (int it = 0; it < 8; ++it) {
            const float* ub = Up + ((size_t)(b * 64 + r0 + it * 8)) * 512 + cc * 8;
            u0[it] = *(const float4*)(ub);
            u1[it] = *(const float4*)(ub + 4);
        }
        const float* vA = Vp + ((size_t)(b * 64 + p0)) * 512 + cc * 8;
        const float* vB = Vp + ((size_t)(b * 64 + p1)) * 512 + cc * 8;
        float4 vA0 = *(const float4*)(vA), vA1 = *(const float4*)(vA + 4);
        float4 vB0 = *(const float4*)(vB), vB1 = *(const float4*)(vB + 4);
#pragma unroll
        for (int it = 0; it < 8; ++it) {
            int row = r0 + it * 8;          // q
            int off = row * 1024 + ((cc * 16) ^ ((row & 15) << 4));
            uint4 w;
            w.x = cvt_pk(fmaxf(u0[it].x + vA0.x, 0.f), fmaxf(u0[it].y + vA0.y, 0.f));
            w.y = cvt_pk(fmaxf(u0[it].z + vA0.z, 0.f), fmaxf(u0[it].w + vA0.w, 0.f));
            w.z = cvt_pk(fmaxf(u1[it].x + vA1.x, 0.f), fmaxf(u1[it].y + vA1.y, 0.f));
            w.w = cvt_pk(fmaxf(u1[it].z + vA1.z, 0.f), fmaxf(u1[it].w + vA1.w, 0.f));
            *(uint4*)(&T0[off]) = w;
            w.x = cvt_pk(fmaxf(u0[it].x + vB0.x, 0.f), fmaxf(u0[it].y + vB0.y, 0.f));
            w.y = cvt_pk(fmaxf(u0[it].z + vB0.z, 0.f), fmaxf(u0[it].w + vB0.w, 0.f));
            w.z = cvt_pk(fmaxf(u1[it].x + vB1.x, 0.f), fmaxf(u1[it].y + vB1.y, 0.f));
            w.w = cvt_pk(fmaxf(u1[it].z + vB1.z, 0.f), fmaxf(u1[it].w + vB1.w, 0.f));
            *(uint4*)(&T1[off]) = w;
        }
    }
    __syncthreads();

    const int arow0 = l31 * 1024;
    const int arow1 = (l31 + 32) * 1024;

    // ---- GEMM1 (swapped): acc[t][hf][qf] = D1[h, q]; depth-2 W prefetch ----
    f32x16 acc[2][2][2];
#pragma unroll
    for (int t = 0; t < 2; ++t)
#pragma unroll
        for (int i = 0; i < 2; ++i)
#pragma unroll
            for (int j = 0; j < 2; ++j) acc[t][i][j] = (f32x16)0.f;

    {
        const unsigned short* wb = W1s + ((size_t)(lg * 512 + wcol + l31)) * 8;
        short8 wc0[2], wc1[2];
        wc0[0] = *(const short8*)(wb);
        wc1[0] = *(const short8*)(wb + 256);
        wc0[1] = *(const short8*)(wb + 8192);
        wc1[1] = *(const short8*)(wb + 8192 + 256);
        __builtin_amdgcn_s_setprio(1);
#pragma unroll
        for (int ks = 0; ks < 32; ++ks) {
            const int par = ks & 1;
            short8 cw0 = wc0[par], cw1 = wc1[par];
            if (ks < 30) {
                const unsigned short* np = wb + (size_t)(ks + 2) * 8192;
                wc0[par] = *(const short8*)(np);
                wc1[par] = *(const short8*)(np + 256);
            }
            int achunk = (ks * 32 + lg * 16) ^ swz;
            short8 a00 = *(const short8*)(&T0[arow0 + achunk]);
            short8 a01 = *(const short8*)(&T0[arow1 + achunk]);
            short8 a10 = *(const short8*)(&T1[arow0 + achunk]);
            short8 a11 = *(const short8*)(&T1[arow1 + achunk]);
            acc[0][0][0] = __builtin_amdgcn_mfma_f32_32x32x16_bf16(cw0, a00, acc[0][0][0], 0, 0, 0);
            acc[0][1][0] = __builtin_amdgcn_mfma_f32_32x32x16_bf16(cw1, a00, acc[0][1][0], 0, 0, 0);
            acc[0][0][1] = __builtin_amdgcn_mfma_f32_32x32x16_bf16(cw0, a01, acc[0][0][1], 0, 0, 0);
            acc[0][1][1] = __builtin_amdgcn_mfma_f32_32x32x16_bf16(cw1, a01, acc[0][1][1], 0, 0, 0);
            acc[1][0][0] = __builtin_amdgcn_mfma_f32_32x32x16_bf16(cw0, a10, acc[1][0][0], 0, 0, 0);
            acc[1][1][0] = __builtin_amdgcn_mfma_f32_32x32x16_bf16(cw1, a10, acc[1][1][0], 0, 0, 0);
            acc[1][0][1] = __builtin_amdgcn_mfma_f32_32x32x16_bf16(cw0, a11, acc[1][0][1], 0, 0, 0);
            acc[1][1][1] = __builtin_amdgcn_mfma_f32_32x32x16_bf16(cw1, a11, acc[1][1][1], 0, 0, 0);
        }
        __builtin_amdgcn_s_setprio(0);
    }
    __syncthreads();   // everyone done READING h0

    // ---- h1 = relu(acc + b1) -> bf16 back into T0/T1 ----
    // acc[t][hf][qf] reg r: h = wcol + hf*32 + (r&3) + 8*(r>>2) + 4*lg, q = qf*32 + l31
    {
#pragma unroll
        for (int hf = 0; hf < 2; ++hf) {
#pragma unroll
            for (int g = 0; g < 4; ++g) {
                int h = wcol + hf * 32 + g * 8 + 4 * lg;
                float4 bb = *(const float4*)(b1 + h);
#pragma unroll
                for (int t = 0; t < 2; ++t) {
#pragma unroll
                    for (int qf = 0; qf < 2; ++qf) {
                        int q = qf * 32 + l31;
                        float a0 = fmaxf(acc[t][hf][qf][g * 4 + 0] + bb.x, 0.f);
                        float a1 = fmaxf(acc[t][hf][qf][g * 4 + 1] + bb.y, 0.f);
                        float a2 = fmaxf(acc[t][hf][qf][g * 4 + 2] + bb.z, 0.f);
                        float a3 = fmaxf(acc[t][hf][qf][g * 4 + 3] + bb.w, 0.f);
                        uint2 pk;
                        pk.x = cvt_pk(a0, a1);
                        pk.y = cvt_pk(a2, a3);
                        int off = q * 1024 + ((h * 2) ^ ((q & 15) << 4));
                        unsigned char* Tt = t ? T1 : T0;
                        *(uint2*)(&Tt[off]) = pk;
                    }
                }
            }
        }
    }
    __syncthreads();   // h1 complete

    // ---- GEMM2 (normal): acc2[t][rf][cf] = D2[q, h2]; depth-2 W prefetch ----
    f32x16 acc2[2][2][2];
#pragma unroll
    for (int t = 0; t < 2; ++t)
#pragma unroll
        for (int i = 0; i < 2; ++i)
#pragma unroll
            for (int j = 0; j < 2; ++j) acc2[t][i][j] = (f32x16)0.f;

    {
        const unsigned short* wb = W2s + ((size_t)(lg * 512 + wcol + l31)) * 8;
        short8 wc0[2], wc1[2];
        wc0[0] = *(const short8*)(wb);
        wc1[0] = *(const short8*)(wb + 256);
        wc0[1] = *(const short8*)(wb + 8192);
        wc1[1] = *(const short8*)(wb + 8192 + 256);
        __builtin_amdgcn_s_setprio(1);
#pragma unroll
        for (int ks = 0; ks < 32; ++ks) {
            const int par = ks & 1;
            short8 cw0 = wc0[par], cw1 = wc1[par];
            if (ks < 30) {
                const unsigned short* np = wb + (size_t)(ks + 2) * 8192;
                wc0[par] = *(const short8*)(np);
                wc1[par] = *(const short8*)(np + 256);
            }
            int achunk = (ks * 32 + lg * 16) ^ swz;
            short8 a00 = *(const short8*)(&T0[arow0 + achunk]);
            short8 a01 = *(const short8*)(&T0[arow1 + achunk]);
            short8 a10 = *(const short8*)(&T1[arow0 + achunk]);
            short8 a11 = *(const short8*)(&T1[arow1 + achunk]);
            acc2[0][0][0] = __builtin_amdgcn_mfma_f32_32x32x16_bf16(a00, cw0, acc2[0][0][0], 0, 0, 0);
            acc2[0][1][0] = __builtin_amdgcn_mfma_f32_32x32x16_bf16(a01, cw0, acc2[0][1][0], 0, 0, 0);
            acc2[0][0][1] = __builtin_amdgcn_mfma_f32_32x32x16_bf16(a00, cw1, acc2[0][0][1], 0, 0, 0);
            acc2[0][1][1] = __builtin_amdgcn_mfma_f32_32x32x16_bf16(a01, cw1, acc2[0][1][1], 0, 0, 0);
            acc2[1][0][0] = __builtin_amdgcn_mfma_f32_32x32x16_bf16(a10, cw0, acc2[1][0][0], 0, 0, 0);
            acc2[1][1][0] = __builtin_amdgcn_mfma_f32_32x32x16_bf16(a11, cw0, acc2[1][1][0], 0, 0, 0);
            acc2[1][0][1] = __builtin_amdgcn_mfma_f32_32x32x16_bf16(a10, cw1, acc2[1][0][1], 0, 0, 0);
            acc2[1][1][1] = __builtin_amdgcn_mfma_f32_32x32x16_bf16(a11, cw1, acc2[1][1][1], 0, 0, 0);
        }
        __builtin_amdgcn_s_setprio(0);
    }

    // ---- relations = relu(acc2 + b2); column-sum over 128 pair-rows ----
    {
        float s[2];
#pragma unroll
        for (int cf = 0; cf < 2; ++cf) {
            int col = wcol + cf * 32 + l31;
            float bias = b2[col];
            float tt = 0.f;
#pragma unroll
            for (int t = 0; t < 2; ++t)
#pragma unroll
                for (int rf = 0; rf < 2; ++rf)
#pragma unroll
                    for (int reg = 0; reg < 16; ++reg)
                        tt += fmaxf(acc2[t][rf][cf][reg] + bias, 0.f);
            tt += __shfl_xor(tt, 32);
            s[cf] = tt;
        }
        if (lane < 32) {
            unsafeAtomicAdd(&emb[b * 512 + wcol + lane], s[0]);
            unsafeAtomicAdd(&emb[b * 512 + wcol + 32 + lane], s[1]);
        }
    }
}

// ---------------------------------------------------------------------------
// Kernel 3: hs = relu(emb @ fW0 + fb0). 256 blocks = (b, 8 slices of 64 cols).
// ---------------------------------------------------------------------------
__global__ __launch_bounds__(256) void f0_kernel(
    const float* __restrict__ emb, const float* __restrict__ fW0,
    const float* __restrict__ fb0, float* __restrict__ hs)
{
    __shared__ float es[512];
    __shared__ float red[256];
    const int b = blockIdx.x >> 3, s = blockIdx.x & 7;
    const int t = threadIdx.x;
    const int colL = t & 63, cg = t >> 6;
    es[t] = emb[b * 512 + t];
    es[t + 256] = emb[b * 512 + 256 + t];
    __syncthreads();
    const int col = s * 64 + colL;
    float a = 0.f;
    const int c0 = cg * 128;
#pragma unroll 4
    for (int c = c0; c < c0 + 128; ++c)
        a += es[c] * fW0[(size_t)c * 512 + col];
    red[t] = a;
    __syncthreads();
    if (t < 64) {
        float r = red[t] + red[t + 64] + red[t + 128] + red[t + 192] + fb0[col];
        hs[b * 512 + col] = fmaxf(r, 0.f);
    }
}

// ---------------------------------------------------------------------------
// Kernel 4: out = hs @ fW1 + fb1. 128 blocks = (b, 4 slices of 64 cols).
// ---------------------------------------------------------------------------
__global__ __launch_bounds__(256) void f1_kernel(
    const float* __restrict__ hs, const float* __restrict__ fW1,
    const float* __restrict__ fb1, float* __restrict__ out)
{
    __shared__ float es[512];
    __shared__ float red[256];
    const int b = blockIdx.x >> 2, s = blockIdx.x & 3;
    const int t = threadIdx.x;
    const int colL = t & 63, cg = t >> 6;
    es[t] = hs[b * 512 + t];
    es[t + 256] = hs[b * 512 + 256 + t];
    __syncthreads();
    const int col = s * 64 + colL;
    float a = 0.f;
    const int c0 = cg * 128;
#pragma unroll 4
    for (int c = c0; c < c0 + 128; ++c)
        a += es[c] * fW1[(size_t)c * 256 + col];
    red[t] = a;
    __syncthreads();
    if (t < 64) {
        out[b * 256 + col] = red[t] + red[t + 64] + red[t + 128] + red[t + 192] + fb1[col];
    }
}

// ---------------------------------------------------------------------------
extern "C" void kernel_launch(void* const* d_in, const int* in_sizes, int n_in,
                              void* d_out, int out_size, void* d_ws, size_t ws_size,
                              hipStream_t stream)
{
    const float* x   = (const float*)d_in[0];
    const float* gW0 = (const float*)d_in[1];
    const float* gb0 = (const float*)d_in[2];
    const float* gW1 = (const float*)d_in[3];
    const float* gb1 = (const float*)d_in[4];
    const float* gW2 = (const float*)d_in[5];
    const float* gb2 = (const float*)d_in[6];
    const float* fW0 = (const float*)d_in[7];
    const float* fb0 = (const float*)d_in[8];
    const float* fW1 = (const float*)d_in[9];
    const float* fb1 = (const float*)d_in[10];
    float* out = (float*)d_out;

    char* ws = (char*)d_ws;
    float* Up           = (float*)(ws);                                   // 4 MB
    float* Vp           = (float*)(ws + (4 << 20));                       // 4 MB
    unsigned short* W1s = (unsigned short*)(ws + (8 << 20));              // 512 KB
    unsigned short* W2s = (unsigned short*)(ws + (8 << 20) + (512 << 10));// 512 KB
    float* emb          = (float*)(ws + (9 << 20));                       // 64 KB
    float* hs           = (float*)(ws + (9 << 20) + (64 << 10));          // 64 KB

    pre_kernel<<<384, 512, 0, stream>>>(x, gW0, gb0, gW1, gW2, Up, Vp, W1s, W2s, emb);
    main_kernel<<<1024, 512, 131072, stream>>>(Up, Vp, W1s, W2s, gb1, gb2, emb);
    f0_kernel<<<256, 256, 0, stream>>>(emb, fW0, fb0, hs);
    f1_kernel<<<128, 256, 0, stream>>>(hs, fW1, fb1, out);
}